// Round 4
// baseline (2076.182 us; speedup 1.0000x reference)
//
#include <hip/hip_runtime.h>
#include <hip/hip_bf16.h>

#define N0 200000
#define N1 150000
#define N2 120000
#define N3 100000
#define E0 2000000
#define E1 1000000
#define E2 500000
#define ESUB 250000

// per-node CSR only for e1/e2 now: cnt12/offs12 layout [c2 | c1]
#define IC2 0
#define IC1 N3
#define LT12 (N3 + N2)                 // 220000
#define NBLK12 ((LT12 + 2047) / 2048)  // 108

// coarse buckets: 512 nodes per bucket (node >> 9)
#define NC2  ((N3 + 511) / 512)      // 196
#define NC1  ((N2 + 511) / 512)      // 235
#define NC0B ((N1 + 511) / 512)      // 293  (e0 buckets per side)
#define NB0  (2 * NC0B)              // 586  (S side then D side)

#define BINCHUNK 4096

typedef float f32x4 __attribute__((ext_vector_type(4)));
typedef __bf16 bf16x8 __attribute__((ext_vector_type(8)));

// ---------------- e0 bucket-level counting (no per-node CSR for layer 0) ----------------
__global__ __launch_bounds__(256) void k_cntb0(const int* __restrict__ src, const int* __restrict__ dst,
                                               int* __restrict__ bcnt) {
    __shared__ int lcnt[1024];
    int t = threadIdx.x;
#pragma unroll
    for (int j = 0; j < 4; j++) lcnt[t + j * 256] = 0;
    __syncthreads();
    int e0 = blockIdx.x * BINCHUNK;
    int e1 = E0 - e0; if (e1 > BINCHUNK) e1 = BINCHUNK; e1 += e0;
    for (int i = e0 + t; i < e1; i += 256) {
        int s = src[i];
        if (s < N1) atomicAdd(&lcnt[s >> 9], 1);
        atomicAdd(&lcnt[512 + (dst[i] >> 9)], 1);
    }
    __syncthreads();
    for (int b = t; b < 1024; b += 256) {
        int c = lcnt[b];
        if (c > 0) atomicAdd(&bcnt[(b >= 512 ? NC0B : 0) + (b & 511)], c);
    }
}

// ---------------- scan of 586 bucket counts -> boffs[587] (single block) ----------------
__global__ __launch_bounds__(256) void k_bscan(const int* __restrict__ bcnt, int* __restrict__ boffs) {
    __shared__ int A[768], B[768];
    int t = threadIdx.x;
    for (int i = t; i < 768; i += 256) A[i] = (i < NB0) ? bcnt[i] : 0;
    __syncthreads();
    int* cur = A; int* nxt = B;
    for (int off = 1; off < 768; off <<= 1) {
        for (int i = t; i < 768; i += 256) nxt[i] = cur[i] + (i >= off ? cur[i - off] : 0);
        __syncthreads();
        int* tmp = cur; cur = nxt; nxt = tmp;
    }
    for (int i = t; i < NB0; i += 256) boffs[i + 1] = cur[i];
    if (t == 0) boffs[0] = 0;
}

// ---------------- counting for e1/e2 (per-node CSR + out-degree) ----------------
__global__ void k_cnt2(const int* __restrict__ src, const int* __restrict__ dst, int n,
                       int* __restrict__ dego, int* __restrict__ cnt, int cbase) {
    int i = blockIdx.x * blockDim.x + threadIdx.x;
    if (i >= n) return;
    atomicAdd(&dego[src[i]], 1);
    atomicAdd(&cnt[cbase + dst[i]], 1);
}

// ---------------- exclusive scan of cnt12 (3-kernel hierarchical, exact) ----------------
__global__ __launch_bounds__(256) void k_scan1(const int* __restrict__ cnt,
                                               int* __restrict__ offs, int* __restrict__ bsum) {
    __shared__ int ts[256];
    int t = threadIdx.x;
    int base = blockIdx.x * 2048 + t * 8;
    int loc[8];
    int s = 0;
#pragma unroll
    for (int j = 0; j < 8; j++) {
        int v = (base + j < LT12) ? cnt[base + j] : 0;
        loc[j] = s; s += v;
    }
    ts[t] = s;
    __syncthreads();
    for (int off = 1; off < 256; off <<= 1) {
        int x = (t >= off) ? ts[t - off] : 0;
        __syncthreads();
        ts[t] += x;
        __syncthreads();
    }
    int excl = ts[t] - s;
#pragma unroll
    for (int j = 0; j < 8; j++)
        if (base + j < LT12) offs[base + j] = excl + loc[j];
    if (t == 255) bsum[blockIdx.x] = ts[255];
}

__global__ __launch_bounds__(256) void k_scan2(const int* __restrict__ bsum,
                                               int* __restrict__ bscan) {
    __shared__ int ts[256];
    int t = threadIdx.x;
    int v = (t < NBLK12) ? bsum[t] : 0;
    ts[t] = v;
    __syncthreads();
    for (int off = 1; off < 256; off <<= 1) {
        int x = (t >= off) ? ts[t - off] : 0;
        __syncthreads();
        ts[t] += x;
        __syncthreads();
    }
    if (t < NBLK12) bscan[t] = ts[t] - v;
}

__global__ void k_scan3(int* __restrict__ offs, const int* __restrict__ bscan,
                        const int* __restrict__ bsum) {
    int i = blockIdx.x * 256 + threadIdx.x;
    if (i < LT12) offs[i] += bscan[i >> 11];
    if (i == 0) offs[LT12] = bscan[NBLK12 - 1] + bsum[NBLK12 - 1];
}

// ---------------- two-level binning (e1/e2): pass A into coarse pool ----------------
// Entry packs (node & 511) << 18 | payload (payload < 2^18).
__global__ __launch_bounds__(256) void k_binA(const int* __restrict__ dst, const int* __restrict__ aux,
                                              int n,
                                              const int* __restrict__ offs, int cbase,
                                              int* __restrict__ ccur, int ccbase,
                                              int* __restrict__ cpool) {
    __shared__ int lcnt[512], lbase[512], lcur[512];
    int t = threadIdx.x;
    lcnt[t] = 0; lcnt[t + 256] = 0;
    lcur[t] = 0; lcur[t + 256] = 0;
    __syncthreads();
    int e0 = blockIdx.x * BINCHUNK;
    int e1 = n - e0; if (e1 > BINCHUNK) e1 = BINCHUNK; e1 += e0;
    for (int i = e0 + t; i < e1; i += 256) {
        atomicAdd(&lcnt[dst[i] >> 9], 1);
    }
    __syncthreads();
    for (int b = t; b < 512; b += 256) {
        int c = lcnt[b];
        if (c > 0) lbase[b] = offs[cbase + (b << 9)] + atomicAdd(&ccur[ccbase + b], c);
    }
    __syncthreads();
    for (int i = e0 + t; i < e1; i += 256) {
        int d = dst[i];
        int b = d >> 9;
        int r = atomicAdd(&lcur[b], 1);
        cpool[lbase[b] + r] = ((d & 511) << 18) | aux[i];
    }
}

// ---------------- e0 pass A: both sides in one read; dense runs at BUCKET offsets ----------------
__global__ __launch_bounds__(256) void k_binA0b(const int* __restrict__ typ,
                                                const int* __restrict__ src, const int* __restrict__ dst,
                                                const int* __restrict__ boffs,
                                                int* __restrict__ bcur, int* __restrict__ cpool0) {
    __shared__ int lcnt[1024], lbase[1024], lcur[1024];
    int t = threadIdx.x;
#pragma unroll
    for (int j = 0; j < 4; j++) { lcnt[t + j * 256] = 0; lcur[t + j * 256] = 0; }
    __syncthreads();
    int e0 = blockIdx.x * BINCHUNK;
    int e1 = E0 - e0; if (e1 > BINCHUNK) e1 = BINCHUNK; e1 += e0;
    for (int i = e0 + t; i < e1; i += 256) {
        int s = src[i];
        if (s < N1) atomicAdd(&lcnt[s >> 9], 1);
        atomicAdd(&lcnt[512 + (dst[i] >> 9)], 1);
    }
    __syncthreads();
    for (int b = t; b < 1024; b += 256) {
        int c = lcnt[b];
        if (c > 0) {
            int idx = (b >= 512 ? NC0B : 0) + (b & 511);
            lbase[b] = boffs[idx] + atomicAdd(&bcur[idx], c);
        }
    }
    __syncthreads();
    for (int i = e0 + t; i < e1; i += 256) {
        int ty = typ[i];
        int s = src[i];
        if (s < N1) {
            int b = s >> 9;
            int r = atomicAdd(&lcur[b], 1);
            cpool0[lbase[b] + r] = ((s & 511) << 18) | ty;
        }
        int d = dst[i];
        int b2 = 512 + (d >> 9);
        int r2 = atomicAdd(&lcur[b2], 1);
        cpool0[lbase[b2] + r2] = ((d & 511) << 18) | ty;
    }
}

// ---------------- pass B (e1+e2 merged): coarse pool -> exact CSR slots ----------------
__global__ __launch_bounds__(256) void k_binB2(const int* __restrict__ offs,
                                               const int* __restrict__ cpool, int* __restrict__ pool) {
    __shared__ int lofs[512], lcur[512];
    int t = threadIdx.x;
    int blk = blockIdx.x;
    int cbase, n0, n_nodes;
    if (blk < NC2) { cbase = IC2; n0 = blk << 9; n_nodes = N3; }
    else           { cbase = IC1; n0 = (blk - NC2) << 9; n_nodes = N2; }
    int nodes = n_nodes - n0; if (nodes > 512) nodes = 512;
    for (int j = t; j < nodes; j += 256) { lofs[j] = offs[cbase + n0 + j]; lcur[j] = 0; }
    __syncthreads();
    int R0 = offs[cbase + n0];
    int Rend = offs[cbase + n0 + nodes];
    for (int i = R0 + t; i < Rend; i += 256) {
        int p = cpool[i];
        int low = p >> 18;
        int r = atomicAdd(&lcur[low], 1);
        pool[lofs[low] + r] = p & 0x3FFFF;
    }
}

// ---------------- layer 0, bucket-resident: LDS-accumulate rel_emb sums, matvec, write h1 ----------------
// One block per 512-node bucket; side 0 = out(src) with W_out, side 1 = in(dst) with W_in.
__global__ __launch_bounds__(256) void k_layer0b(const int* __restrict__ boffs,
                                                 const int* __restrict__ cpool0,
                                                 const float* __restrict__ rel_emb,
                                                 const float* __restrict__ W_out, const float* __restrict__ b_out,
                                                 const float* __restrict__ W_in, const float* __restrict__ b_in,
                                                 const int* __restrict__ deg1o, float* __restrict__ h1) {
    __shared__ float acc[512][32];   // 64 KB
    __shared__ int lcnt[512];
    int t = threadIdx.x;
    int b = blockIdx.x;
    int nbase = b << 9;
    int lane = t & 63;
    int wave = t >> 6;
    int k = lane & 31;
    int hw = lane >> 5;
    for (int side = 0; side < 2; side++) {
        for (int i = t; i < 512 * 32; i += 256) ((float*)acc)[i] = 0.0f;
        for (int i = t; i < 512; i += 256) lcnt[i] = 0;
        __syncthreads();
        int R0 = boffs[side * NC0B + b];
        int R1 = boffs[side * NC0B + b + 1];
        for (int cb = R0 + wave * 64; cb < R1; cb += 256) {
            int rem = R1 - cb; if (rem > 64) rem = 64;
            int ent = (lane < rem) ? cpool0[cb + lane] : 0;
#pragma unroll 2
            for (int j = 0; j < 64 && j < rem; j += 2) {
                int jj = j + hw;
                int e = __shfl(ent, (jj < rem) ? jj : 0, 64);
                if (jj < rem) {
                    int node = e >> 18;
                    int ty = e & 0x3FFFF;
                    atomicAdd(&acc[node][k], rel_emb[ty * 32 + k]);
                    if (k == 0) atomicAdd(&lcnt[node], 1);
                }
            }
        }
        __syncthreads();
        // matvec + write: 8 groups of 32 lanes; group g handles nodes g, g+8, ...
        const float* W = side ? W_in : W_out;
        float bias = side ? b_in[t & 31] : b_out[t & 31];
        int j = t & 31;
        int g = t >> 5;
        for (int nl = g; nl < 512; nl += 8) {
            int n = nbase + nl;
            if (n >= N1) break;
            int c = lcnt[nl];
            float r = 0.0f;
            if (c > 0) {
                float d = 0.0f;
#pragma unroll
                for (int kk = 0; kk < 32; kk++) d += acc[nl][kk] * W[kk * 32 + j];
                r = d / (float)c + bias;
            }
            h1[(size_t)n * 64 + side * 32 + j] = r * rsqrtf(fmaxf((float)deg1o[n], 1.0f));
        }
        __syncthreads();
    }
}

// ---------------- conv1 with fused gather (unroll x4), writes h2 as bf16 ----------------
__global__ __launch_bounds__(256) void k_conv1g(const float* __restrict__ h1,
                                                const int* __restrict__ cnt, const int* __restrict__ offs,
                                                const int* __restrict__ pool, const int* __restrict__ deg2o,
                                                const float* __restrict__ W1, const float* __restrict__ b1,
                                                __bf16* __restrict__ h2b) {
    __shared__ float row[8][64];
    int base = blockIdx.x * 8;
    int t = threadIdx.x;
    int wave = t >> 6, lane = t & 63;
#pragma unroll
    for (int rr = 0; rr < 2; rr++) {
        int m = wave * 2 + rr;
        int rg = base + m;                       // grid exact: rg < N2
        int dg = cnt[IC1 + rg];
        int off = offs[IC1 + rg];
        float acc = 0.0f;
        for (int cb = 0; cb < dg; cb += 64) {
            int rem = dg - cb; if (rem > 64) rem = 64;
            int s_all = (lane < rem) ? pool[off + cb + lane] : 0;
            int i = 0;
            for (; i + 4 <= rem; i += 4) {
                int s0 = __shfl(s_all, i,     64);
                int s1 = __shfl(s_all, i + 1, 64);
                int s2 = __shfl(s_all, i + 2, 64);
                int s3 = __shfl(s_all, i + 3, 64);
                float a0 = h1[(size_t)s0 * 64 + lane];
                float a1 = h1[(size_t)s1 * 64 + lane];
                float a2 = h1[(size_t)s2 * 64 + lane];
                float a3 = h1[(size_t)s3 * 64 + lane];
                acc += a0; acc += a1; acc += a2; acc += a3;
            }
            for (; i < rem; i++) {
                int s = __shfl(s_all, i, 64);
                acc += h1[(size_t)s * 64 + lane];
            }
        }
        row[m][lane] = acc * rsqrtf(fmaxf((float)dg, 1.0f));
    }
    __syncthreads();
    float acc8[8] = {0, 0, 0, 0, 0, 0, 0, 0};
    for (int k = 0; k < 64; k++) {
        float w = W1[k * 256 + t];
#pragma unroll
        for (int m = 0; m < 8; m++) acc8[m] += row[m][k] * w;
    }
    float bb = b1[t];
#pragma unroll
    for (int m = 0; m < 8; m++) {
        float v = fmaxf(acc8[m] + bb, 0.0f) * rsqrtf(fmaxf((float)deg2o[base + m], 1.0f));
        h2b[(size_t)(base + m) * 256 + t] = (__bf16)v;
    }
}

// ---------------- pack W (K x 256 f32, row-major) into MFMA B-fragment order (bf16) ----------------
__global__ void k_pack(const float* __restrict__ W, __bf16* __restrict__ Wp, int ksteps) {
    int idx = blockIdx.x * 256 + threadIdx.x;
    int j = idx & 7;
    int lane = (idx >> 3) & 63;
    int rest = idx >> 9;
    int ks = rest % ksteps;
    int tn = rest / ksteps;
    int k = ks * 32 + ((lane >> 4) * 8) + j;
    int n = tn * 16 + (lane & 15);
    Wp[idx] = (__bf16)W[k * 256 + n];
}

// ---------------- conv2 MFMA with fused gather (bf16 h2, unroll x4) ----------------
__global__ __launch_bounds__(256) void k_conv2g(const __bf16* __restrict__ h2b,
                                                const int* __restrict__ cnt, const int* __restrict__ offs,
                                                const int* __restrict__ pool,
                                                const __bf16* __restrict__ W2p,
                                                const float* __restrict__ b2v,
                                                __bf16* __restrict__ x3b) {
    __shared__ __bf16 At[64][264];   // +8 pad -> 2-way LDS conflicts only
    int t = threadIdx.x;
    int base = blockIdx.x * 64;
    int wave = t >> 6, lane = t & 63;
#pragma unroll 1
    for (int rr = 0; rr < 16; rr++) {
        int row = wave * 16 + rr;
        int rg = base + row;
        float a0 = 0.f, a1 = 0.f, a2 = 0.f, a3 = 0.f;
        int dg = 0;
        if (rg < N3) {
            dg = cnt[IC2 + rg];
            int off = offs[IC2 + rg];
            for (int cb = 0; cb < dg; cb += 64) {
                int rem = dg - cb; if (rem > 64) rem = 64;
                int s_all = (lane < rem) ? pool[off + cb + lane] : 0;
                int i = 0;
                for (; i + 4 <= rem; i += 4) {
                    int s0 = __shfl(s_all, i,     64);
                    int s1 = __shfl(s_all, i + 1, 64);
                    int s2 = __shfl(s_all, i + 2, 64);
                    int s3 = __shfl(s_all, i + 3, 64);
                    union { ushort4 u; __bf16 b[4]; } v0, v1, v2, v3;
                    v0.u = *(const ushort4*)(h2b + (size_t)s0 * 256 + lane * 4);
                    v1.u = *(const ushort4*)(h2b + (size_t)s1 * 256 + lane * 4);
                    v2.u = *(const ushort4*)(h2b + (size_t)s2 * 256 + lane * 4);
                    v3.u = *(const ushort4*)(h2b + (size_t)s3 * 256 + lane * 4);
                    a0 += ((float)v0.b[0] + (float)v1.b[0]) + ((float)v2.b[0] + (float)v3.b[0]);
                    a1 += ((float)v0.b[1] + (float)v1.b[1]) + ((float)v2.b[1] + (float)v3.b[1]);
                    a2 += ((float)v0.b[2] + (float)v1.b[2]) + ((float)v2.b[2] + (float)v3.b[2]);
                    a3 += ((float)v0.b[3] + (float)v1.b[3]) + ((float)v2.b[3] + (float)v3.b[3]);
                }
                for (; i < rem; i++) {
                    int s0 = __shfl(s_all, i, 64);
                    union { ushort4 u; __bf16 b[4]; } v0;
                    v0.u = *(const ushort4*)(h2b + (size_t)s0 * 256 + lane * 4);
                    a0 += (float)v0.b[0]; a1 += (float)v0.b[1];
                    a2 += (float)v0.b[2]; a3 += (float)v0.b[3];
                }
            }
        }
        float sc = rsqrtf(fmaxf((float)dg, 1.0f));
        union { __bf16 b[4]; uint2 u; } cv;
        cv.b[0] = (__bf16)(a0 * sc); cv.b[1] = (__bf16)(a1 * sc);
        cv.b[2] = (__bf16)(a2 * sc); cv.b[3] = (__bf16)(a3 * sc);
        *(uint2*)&At[row][lane * 4] = cv.u;
    }
    __syncthreads();
    int q = lane >> 4, r16 = lane & 15;
    f32x4 acc[4][4] = {};
    for (int ks = 0; ks < 8; ks++) {
        bf16x8 a[4], b[4];
        int ko = ks * 32 + q * 8;
#pragma unroll
        for (int mt = 0; mt < 4; mt++)
            a[mt] = *(const bf16x8*)&At[mt * 16 + r16][ko];
#pragma unroll
        for (int i = 0; i < 4; i++) {
            int tn = wave * 4 + i;
            b[i] = *(const bf16x8*)&W2p[((size_t)(tn * 8 + ks) * 64 + lane) * 8];
        }
#pragma unroll
        for (int mt = 0; mt < 4; mt++)
#pragma unroll
            for (int i = 0; i < 4; i++)
                acc[mt][i] = __builtin_amdgcn_mfma_f32_16x16x32_bf16(a[mt], b[i], acc[mt][i], 0, 0, 0);
    }
#pragma unroll
    for (int mt = 0; mt < 4; mt++) {
#pragma unroll
        for (int i = 0; i < 4; i++) {
            int col = (wave * 4 + i) * 16 + r16;
            float bb = b2v[col];
#pragma unroll
            for (int rr = 0; rr < 4; rr++) {
                int row = base + mt * 16 + q * 4 + rr;
                if (row < N3)
                    x3b[(size_t)row * 256 + col] = (__bf16)fmaxf(acc[mt][i][rr] + bb, 0.0f);
            }
        }
    }
}

// ---------------- final via MFMA: out = [x3b[ss], x3b[sd]] @ Wfc + bfc ----------------
__global__ __launch_bounds__(256) void k_final_mfma(const int* __restrict__ ss, const int* __restrict__ sd,
                                                    const __bf16* __restrict__ x3b,
                                                    const __bf16* __restrict__ Wp,
                                                    const float* __restrict__ bfc,
                                                    float* __restrict__ out) {
    __shared__ __bf16 At[64][520];   // +8 pad -> 2-way LDS conflicts only
    __shared__ int eidx[128];
    int t = threadIdx.x;
    int base = blockIdx.x * 64;
    if (t < 64)       { int e = base + t;      eidx[t] = ss[e < ESUB ? e : ESUB - 1]; }
    else if (t < 128) { int e = base + t - 64; eidx[t] = sd[e < ESUB ? e : ESUB - 1]; }
    __syncthreads();
#pragma unroll
    for (int it = 0; it < 16; it++) {
        int c = it * 256 + t;       // 0..4095
        int row = c >> 6;           // 0..63
        int cpos = c & 63;          // 16B chunk within 512-elem row
        int half = cpos >> 5;
        int off8 = (cpos & 31) * 8;
        int node = eidx[half * 64 + row];
        uint4 v = *(const uint4*)(x3b + (size_t)node * 256 + off8);
        *(uint4*)&At[row][half * 256 + off8] = v;
    }
    __syncthreads();
    int wave = t >> 6, lane = t & 63;
    int q = lane >> 4, r16 = lane & 15;
    f32x4 acc[4][4] = {};
    for (int ks = 0; ks < 16; ks++) {
        bf16x8 a[4], b[4];
        int ko = ks * 32 + q * 8;
#pragma unroll
        for (int mt = 0; mt < 4; mt++)
            a[mt] = *(const bf16x8*)&At[mt * 16 + r16][ko];
#pragma unroll
        for (int i = 0; i < 4; i++) {
            int tn = wave * 4 + i;
            b[i] = *(const bf16x8*)&Wp[((size_t)(tn * 16 + ks) * 64 + lane) * 8];
        }
#pragma unroll
        for (int mt = 0; mt < 4; mt++)
#pragma unroll
            for (int i = 0; i < 4; i++)
                acc[mt][i] = __builtin_amdgcn_mfma_f32_16x16x32_bf16(a[mt], b[i], acc[mt][i], 0, 0, 0);
    }
#pragma unroll
    for (int mt = 0; mt < 4; mt++) {
#pragma unroll
        for (int i = 0; i < 4; i++) {
            int col = (wave * 4 + i) * 16 + r16;
            float bb = bfc[col];
#pragma unroll
            for (int rr = 0; rr < 4; rr++) {
                int row = base + mt * 16 + q * 4 + rr;
                if (row < ESUB)
                    out[(size_t)row * 256 + col] = acc[mt][i][rr] + bb;
            }
        }
    }
}

extern "C" void kernel_launch(void* const* d_in, const int* in_sizes, int n_in,
                              void* d_out, int out_size, void* d_ws, size_t ws_size,
                              hipStream_t stream) {
    const int* e0_type = (const int*)d_in[0];
    const int* e0_src  = (const int*)d_in[1];
    const int* e0_dst  = (const int*)d_in[2];
    const int* e1_src  = (const int*)d_in[3];
    const int* e1_dst  = (const int*)d_in[4];
    const int* e2_src  = (const int*)d_in[5];
    const int* e2_dst  = (const int*)d_in[6];
    const int* sub_src = (const int*)d_in[7];
    const int* sub_dst = (const int*)d_in[8];
    const float* rel_emb = (const float*)d_in[9];
    const float* W_out   = (const float*)d_in[10];
    const float* b_out   = (const float*)d_in[11];
    const float* W_in    = (const float*)d_in[12];
    const float* b_in    = (const float*)d_in[13];
    const float* W1      = (const float*)d_in[14];
    const float* b1      = (const float*)d_in[15];
    const float* W2      = (const float*)d_in[16];
    const float* b2v     = (const float*)d_in[17];
    const float* Wfc     = (const float*)d_in[18];
    const float* bfc     = (const float*)d_in[19];
    float* out = (float*)d_out;

    // ---- workspace layout (4-byte units), total ~126 MB ----
    // zeroed region first: [bcnt | bcur | ccur12 | cnt12 | deg1o | deg2o]
    int* bcnt   = (int*)d_ws;            // 640 (NB0=586 used)
    int* bcur   = bcnt + 640;            // 640
    int* ccur12 = bcur + 640;            // 512 (NC2+NC1=431 used)
    int* cnt12  = ccur12 + 512;          // LT12
    int* deg1o  = cnt12 + LT12;          // N1
    int* deg2o  = deg1o + N1;            // N2
    // non-zeroed:
    int* boffs  = deg2o + N2;            // NB0+1
    int* offs12 = boffs + 640;           // LT12+1
    int* bsum   = offs12 + LT12 + 1;     // 512
    int* bscan  = bsum + 512;            // 512
    int* cpool0 = bscan + 512;           // 4,000,000 (e0 coarse entries)
    int* cpool12 = cpool0 + 4000000;     // 1,500,000 (e1+e2 coarse entries)
    int* pool12  = cpool12 + 1500000;    // 1,500,000 (e1+e2 CSR)
    float* h1  = (float*)(pool12 + 1500000);         // N1*64 f32
    __bf16* h2b = (__bf16*)(h1 + (size_t)N1 * 64);   // N2*256 bf16
    __bf16* x3b = h2b + (size_t)N2 * 256;            // N3*256 bf16
    __bf16* Wfcp = x3b + (size_t)N3 * 256;           // 512*256 bf16
    __bf16* W2p  = Wfcp + 131072;                    // 256*256 bf16

    const int BT = 256;

    // zero counters (~2 MB contiguous)
    hipMemsetAsync(d_ws, 0, (size_t)(640 + 640 + 512 + LT12 + N1 + N2) * sizeof(int), stream);

    // pack weights (independent of zeroed region)
    k_pack<<<512, BT, 0, stream>>>(Wfc, Wfcp, 16);
    k_pack<<<256, BT, 0, stream>>>(W2, W2p, 8);

    // counting
    int nbA0 = (E0 + BINCHUNK - 1) / BINCHUNK;
    int nbA1 = (E1 + BINCHUNK - 1) / BINCHUNK;
    int nbA2 = (E2 + BINCHUNK - 1) / BINCHUNK;
    k_cntb0<<<nbA0, BT, 0, stream>>>(e0_src, e0_dst, bcnt);
    k_cnt2<<<(E1 + BT - 1) / BT, BT, 0, stream>>>(e1_src, e1_dst, E1, deg1o, cnt12, IC1);
    k_cnt2<<<(E2 + BT - 1) / BT, BT, 0, stream>>>(e2_src, e2_dst, E2, deg2o, cnt12, IC2);

    // scans
    k_bscan<<<1, BT, 0, stream>>>(bcnt, boffs);
    k_scan1<<<NBLK12, BT, 0, stream>>>(cnt12, offs12, bsum);
    k_scan2<<<1, BT, 0, stream>>>(bsum, bscan);
    k_scan3<<<(LT12 + BT - 1) / BT, BT, 0, stream>>>(offs12, bscan, bsum);

    // pass A
    k_binA0b<<<nbA0, BT, 0, stream>>>(e0_type, e0_src, e0_dst, boffs, bcur, cpool0);
    k_binA<<<nbA2, BT, 0, stream>>>(e2_dst, e2_src, E2, offs12, IC2, ccur12, 0, cpool12);
    k_binA<<<nbA1, BT, 0, stream>>>(e1_dst, e1_src, E1, offs12, IC1, ccur12, NC2, cpool12);

    // pass B (e1+e2 merged)
    k_binB2<<<NC2 + NC1, BT, 0, stream>>>(offs12, cpool12, pool12);

    // layer 0 (bucket-resident) -> h1
    k_layer0b<<<NC0B, BT, 0, stream>>>(boffs, cpool0, rel_emb, W_out, b_out, W_in, b_in, deg1o, h1);

    // conv1 (fused gather) -> h2 (bf16)
    k_conv1g<<<N2 / 8, BT, 0, stream>>>(h1, cnt12, offs12, pool12, deg2o, W1, b1, h2b);

    // conv2 (fused gather, MFMA) -> x3b
    k_conv2g<<<(N3 + 63) / 64, BT, 0, stream>>>(h2b, cnt12, offs12, pool12, W2p, b2v, x3b);

    // final edge MLP (MFMA)
    k_final_mfma<<<(ESUB + 63) / 64, BT, 0, stream>>>(sub_src, sub_dst, x3b, Wfcp, bfc, out);
}

// Round 5
// 980.025 us; speedup vs baseline: 2.1185x; 2.1185x over previous
//
#include <hip/hip_runtime.h>
#include <hip/hip_bf16.h>

#define N0 200000
#define N1 150000
#define N2 120000
#define N3 100000
#define E0 2000000
#define E1 1000000
#define E2 500000
#define ESUB 250000

// per-node CSR arrays (cntN/offsN) layout: [c2 | c1 | c0s | c0d]
#define IC2 0
#define IC1 N3
#define I0S (N3 + N2)
#define I0D (N3 + N2 + N1)
#define LALL (N3 + N2 + 2 * N1)     // 520000

// coarse buckets: 512 nodes per bucket (node >> 9), order [B2 | B1 | B0S | B0D]
#define NC2  ((N3 + 511) / 512)      // 196
#define NC1  ((N2 + 511) / 512)      // 235
#define NC0B ((N1 + 511) / 512)      // 293
#define CB2  0
#define CB1  NC2
#define CB0S (NC2 + NC1)             // 431
#define CB0D (NC2 + NC1 + NC0B)      // 724
#define NBALL (NC2 + NC1 + 2 * NC0B) // 1017

#define BINCHUNK 4096
#define POOLCAP (E2 + E1 + 2 * E0)   // 5,500,000 upper bound

typedef float f32x4 __attribute__((ext_vector_type(4)));
typedef __bf16 bf16x8 __attribute__((ext_vector_type(8)));

// ---------------- bucket counting: e0 both sides ----------------
__global__ __launch_bounds__(256) void k_cntb0(const int* __restrict__ src, const int* __restrict__ dst,
                                               int* __restrict__ bcnt) {
    __shared__ int lcnt[1024];
    int t = threadIdx.x;
#pragma unroll
    for (int j = 0; j < 4; j++) lcnt[t + j * 256] = 0;
    __syncthreads();
    int e0 = blockIdx.x * BINCHUNK;
    int e1 = E0 - e0; if (e1 > BINCHUNK) e1 = BINCHUNK; e1 += e0;
    for (int i = e0 + t; i < e1; i += 256) {
        int s = src[i];
        if (s < N1) atomicAdd(&lcnt[s >> 9], 1);
        atomicAdd(&lcnt[512 + (dst[i] >> 9)], 1);
    }
    __syncthreads();
    for (int b = t; b < 1024; b += 256) {
        int c = lcnt[b];
        if (c > 0) atomicAdd(&bcnt[(b >= 512 ? CB0D - 512 : CB0S) + b], c);
    }
}

// ---------------- bucket counting e1/e2 + out-degree ----------------
__global__ __launch_bounds__(256) void k_cnt2b(const int* __restrict__ src, const int* __restrict__ dst,
                                               int n, int* __restrict__ dego,
                                               int* __restrict__ bcnt, int bbase) {
    __shared__ int lcnt[512];
    int t = threadIdx.x;
    lcnt[t] = 0; lcnt[t + 256] = 0;
    __syncthreads();
    int e0 = blockIdx.x * BINCHUNK;
    int e1 = n - e0; if (e1 > BINCHUNK) e1 = BINCHUNK; e1 += e0;
    for (int i = e0 + t; i < e1; i += 256) {
        atomicAdd(&dego[src[i]], 1);
        atomicAdd(&lcnt[dst[i] >> 9], 1);
    }
    __syncthreads();
    for (int b = t; b < 512; b += 256) {
        int c = lcnt[b];
        if (c > 0) atomicAdd(&bcnt[bbase + b], c);
    }
}

// ---------------- scan of 1017 bucket counts -> boffs[1018] (single block) ----------------
__global__ __launch_bounds__(256) void k_bscanA(const int* __restrict__ bcnt, int* __restrict__ boffs) {
    __shared__ int A[1024], B[1024];
    int t = threadIdx.x;
    for (int i = t; i < 1024; i += 256) A[i] = (i < NBALL) ? bcnt[i] : 0;
    __syncthreads();
    int* cur = A; int* nxt = B;
    for (int off = 1; off < 1024; off <<= 1) {
        for (int i = t; i < 1024; i += 256) nxt[i] = cur[i] + (i >= off ? cur[i - off] : 0);
        __syncthreads();
        int* tmp = cur; cur = nxt; nxt = tmp;
    }
    for (int i = t; i < NBALL; i += 256) boffs[i + 1] = cur[i];
    if (t == 0) boffs[0] = 0;
}

// ---------------- pass A (e1/e2): dense coarse runs at bucket offsets ----------------
// Entry packs (node & 511) << 18 | payload (payload < 2^18).
__global__ __launch_bounds__(256) void k_binA(const int* __restrict__ dst, const int* __restrict__ aux,
                                              int n, const int* __restrict__ boffs,
                                              int* __restrict__ bcur, int ccbase,
                                              int* __restrict__ cpool) {
    __shared__ int lcnt[512], lbase[512], lcur[512];
    int t = threadIdx.x;
    lcnt[t] = 0; lcnt[t + 256] = 0;
    lcur[t] = 0; lcur[t + 256] = 0;
    __syncthreads();
    int e0 = blockIdx.x * BINCHUNK;
    int e1 = n - e0; if (e1 > BINCHUNK) e1 = BINCHUNK; e1 += e0;
    for (int i = e0 + t; i < e1; i += 256) {
        atomicAdd(&lcnt[dst[i] >> 9], 1);
    }
    __syncthreads();
    for (int b = t; b < 512; b += 256) {
        int c = lcnt[b];
        if (c > 0) lbase[b] = boffs[ccbase + b] + atomicAdd(&bcur[ccbase + b], c);
    }
    __syncthreads();
    for (int i = e0 + t; i < e1; i += 256) {
        int d = dst[i];
        int b = d >> 9;
        int r = atomicAdd(&lcur[b], 1);
        cpool[lbase[b] + r] = ((d & 511) << 18) | aux[i];
    }
}

// ---------------- pass A (e0): both sides in one read ----------------
__global__ __launch_bounds__(256) void k_binA0b(const int* __restrict__ typ,
                                                const int* __restrict__ src, const int* __restrict__ dst,
                                                const int* __restrict__ boffs,
                                                int* __restrict__ bcur, int* __restrict__ cpool) {
    __shared__ int lcnt[1024], lbase[1024], lcur[1024];
    int t = threadIdx.x;
#pragma unroll
    for (int j = 0; j < 4; j++) { lcnt[t + j * 256] = 0; lcur[t + j * 256] = 0; }
    __syncthreads();
    int e0 = blockIdx.x * BINCHUNK;
    int e1 = E0 - e0; if (e1 > BINCHUNK) e1 = BINCHUNK; e1 += e0;
    for (int i = e0 + t; i < e1; i += 256) {
        int s = src[i];
        if (s < N1) atomicAdd(&lcnt[s >> 9], 1);
        atomicAdd(&lcnt[512 + (dst[i] >> 9)], 1);
    }
    __syncthreads();
    for (int b = t; b < 1024; b += 256) {
        int c = lcnt[b];
        if (c > 0) {
            int idx = (b >= 512 ? CB0D - 512 : CB0S) + b;
            lbase[b] = boffs[idx] + atomicAdd(&bcur[idx], c);
        }
    }
    __syncthreads();
    for (int i = e0 + t; i < e1; i += 256) {
        int ty = typ[i];
        int s = src[i];
        if (s < N1) {
            int b = s >> 9;
            int r = atomicAdd(&lcur[b], 1);
            cpool[lbase[b] + r] = ((s & 511) << 18) | ty;
        }
        int d = dst[i];
        int b2 = 512 + (d >> 9);
        int r2 = atomicAdd(&lcur[b2], 1);
        cpool[lbase[b2] + r2] = ((d & 511) << 18) | ty;
    }
}

// ---------------- pass B (all graphs): coarse region -> node-sorted pool + per-node CSR ----------------
__global__ __launch_bounds__(256) void k_binBall(const int* __restrict__ boffs,
                                                 const int* __restrict__ cpool,
                                                 int* __restrict__ pool,
                                                 int* __restrict__ cntN, int* __restrict__ offsN) {
    __shared__ int lcnt[512], lexc[512];
    int t = threadIdx.x;
    int g = blockIdx.x;
    int cbase, n0, nseg;
    if (g < CB1)       { cbase = IC2; n0 = g << 9;            nseg = N3; }
    else if (g < CB0S) { cbase = IC1; n0 = (g - CB1) << 9;    nseg = N2; }
    else if (g < CB0D) { cbase = I0S; n0 = (g - CB0S) << 9;   nseg = N1; }
    else               { cbase = I0D; n0 = (g - CB0D) << 9;   nseg = N1; }
    int nodes = nseg - n0; if (nodes > 512) nodes = 512;
    lcnt[t] = 0; lcnt[t + 256] = 0;
    __syncthreads();
    int R0 = boffs[g], R1 = boffs[g + 1];
    // pass 1: per-node counts
    for (int i = R0 + t; i < R1; i += 256) atomicAdd(&lcnt[cpool[i] >> 18], 1);
    __syncthreads();
    // inclusive scan of lcnt into lexc (512 entries, 2 per thread, Hillis-Steele)
    lexc[t] = lcnt[t]; lexc[t + 256] = lcnt[t + 256];
    __syncthreads();
    for (int off = 1; off < 512; off <<= 1) {
        int a0 = (t >= off) ? lexc[t - off] : 0;
        int a1 = (t + 256 >= off) ? lexc[t + 256 - off] : 0;
        __syncthreads();
        lexc[t] += a0; lexc[t + 256] += a1;
        __syncthreads();
    }
    // emit per-node CSR; convert lexc to exclusive; reset lcnt as cursor
#pragma unroll
    for (int jj = 0; jj < 2; jj++) {
        int j = t + jj * 256;
        int c = lcnt[j];
        int ex = lexc[j] - c;
        if (j < nodes) { cntN[cbase + n0 + j] = c; offsN[cbase + n0 + j] = R0 + ex; }
        lexc[j] = ex; lcnt[j] = 0;
    }
    __syncthreads();
    // pass 2: scatter payload into node-sorted slots (window L2-dense)
    for (int i = R0 + t; i < R1; i += 256) {
        int p = cpool[i];
        int low = p >> 18;
        int r = atomicAdd(&lcnt[low], 1);
        pool[R0 + lexc[low] + r] = p & 0x3FFFF;
    }
}

// ---------------- layer 0: gather rel_emb means + 32x32 matvecs -> h1 ----------------
// rel_emb (64KB) stays hot in L1/L2; broadcast gather unrolled x4 for ILP.
__global__ __launch_bounds__(256) void k_layer0(const int* __restrict__ cntN, const int* __restrict__ offsN,
                                                const int* __restrict__ pool, const float* __restrict__ rel_emb,
                                                const float* __restrict__ W_out, const float* __restrict__ b_out,
                                                const float* __restrict__ W_in, const float* __restrict__ b_in,
                                                const int* __restrict__ deg1o, float* __restrict__ h1) {
    __shared__ float S[4][64];
    int t = threadIdx.x;
    int nl = t >> 6;
    int lane = t & 63;
    int half = lane >> 5;   // 0 = out(src-agg), 1 = in(dst-agg)
    int k = lane & 31;
    int n = blockIdx.x * 4 + nl;        // grid exact: N1 % 4 == 0
    int ci = (half ? I0D : I0S) + n;
    int dg = cntN[ci];
    int off = offsN[ci];
    float acc = 0.0f;
    for (int cb = 0; cb < dg; cb += 32) {
        int rem = dg - cb; if (rem > 32) rem = 32;
        int ty_all = (k < rem) ? pool[off + cb + k] : 0;
        int i2 = 0;
        for (; i2 + 4 <= rem; i2 += 4) {
            int t0 = __shfl(ty_all, i2,     32);
            int t1 = __shfl(ty_all, i2 + 1, 32);
            int t2 = __shfl(ty_all, i2 + 2, 32);
            int t3 = __shfl(ty_all, i2 + 3, 32);
            float a0 = rel_emb[t0 * 32 + k];
            float a1 = rel_emb[t1 * 32 + k];
            float a2 = rel_emb[t2 * 32 + k];
            float a3 = rel_emb[t3 * 32 + k];
            acc += a0; acc += a1; acc += a2; acc += a3;
        }
        for (; i2 < rem; i2++) {
            int ty = __shfl(ty_all, i2, 32);
            acc += rel_emb[ty * 32 + k];
        }
    }
    S[nl][lane] = (dg > 0) ? acc / (float)dg : 0.0f;
    __syncthreads();
    const float* W = half ? W_in : W_out;
    float b = half ? b_in[k] : b_out[k];
    float r = 0.0f;
    if (dg > 0) {
        float d = 0.0f;
#pragma unroll
        for (int kk = 0; kk < 32; kk++) d += S[nl][half * 32 + kk] * W[kk * 32 + k];
        r = d + b;
    }
    h1[(size_t)n * 64 + lane] = r * rsqrtf(fmaxf((float)deg1o[n], 1.0f));
}

// ---------------- conv1 with fused gather (unroll x4), writes h2 as bf16 ----------------
__global__ __launch_bounds__(256) void k_conv1g(const float* __restrict__ h1,
                                                const int* __restrict__ cntN, const int* __restrict__ offsN,
                                                const int* __restrict__ pool, const int* __restrict__ deg2o,
                                                const float* __restrict__ W1, const float* __restrict__ b1,
                                                __bf16* __restrict__ h2b) {
    __shared__ float row[8][64];
    int base = blockIdx.x * 8;
    int t = threadIdx.x;
    int wave = t >> 6, lane = t & 63;
#pragma unroll
    for (int rr = 0; rr < 2; rr++) {
        int m = wave * 2 + rr;
        int rg = base + m;                       // grid exact: rg < N2
        int dg = cntN[IC1 + rg];
        int off = offsN[IC1 + rg];
        float acc = 0.0f;
        for (int cb = 0; cb < dg; cb += 64) {
            int rem = dg - cb; if (rem > 64) rem = 64;
            int s_all = (lane < rem) ? pool[off + cb + lane] : 0;
            int i = 0;
            for (; i + 4 <= rem; i += 4) {
                int s0 = __shfl(s_all, i,     64);
                int s1 = __shfl(s_all, i + 1, 64);
                int s2 = __shfl(s_all, i + 2, 64);
                int s3 = __shfl(s_all, i + 3, 64);
                float a0 = h1[(size_t)s0 * 64 + lane];
                float a1 = h1[(size_t)s1 * 64 + lane];
                float a2 = h1[(size_t)s2 * 64 + lane];
                float a3 = h1[(size_t)s3 * 64 + lane];
                acc += a0; acc += a1; acc += a2; acc += a3;
            }
            for (; i < rem; i++) {
                int s = __shfl(s_all, i, 64);
                acc += h1[(size_t)s * 64 + lane];
            }
        }
        row[m][lane] = acc * rsqrtf(fmaxf((float)dg, 1.0f));
    }
    __syncthreads();
    float acc8[8] = {0, 0, 0, 0, 0, 0, 0, 0};
    for (int k = 0; k < 64; k++) {
        float w = W1[k * 256 + t];
#pragma unroll
        for (int m = 0; m < 8; m++) acc8[m] += row[m][k] * w;
    }
    float bb = b1[t];
#pragma unroll
    for (int m = 0; m < 8; m++) {
        float v = fmaxf(acc8[m] + bb, 0.0f) * rsqrtf(fmaxf((float)deg2o[base + m], 1.0f));
        h2b[(size_t)(base + m) * 256 + t] = (__bf16)v;
    }
}

// ---------------- pack W (K x 256 f32, row-major) into MFMA B-fragment order (bf16) ----------------
__global__ void k_pack(const float* __restrict__ W, __bf16* __restrict__ Wp, int ksteps) {
    int idx = blockIdx.x * 256 + threadIdx.x;
    int j = idx & 7;
    int lane = (idx >> 3) & 63;
    int rest = idx >> 9;
    int ks = rest % ksteps;
    int tn = rest / ksteps;
    int k = ks * 32 + ((lane >> 4) * 8) + j;
    int n = tn * 16 + (lane & 15);
    Wp[idx] = (__bf16)W[k * 256 + n];
}

// ---------------- conv2 MFMA with fused gather (bf16 h2, unroll x4) ----------------
__global__ __launch_bounds__(256) void k_conv2g(const __bf16* __restrict__ h2b,
                                                const int* __restrict__ cntN, const int* __restrict__ offsN,
                                                const int* __restrict__ pool,
                                                const __bf16* __restrict__ W2p,
                                                const float* __restrict__ b2v,
                                                __bf16* __restrict__ x3b) {
    __shared__ __bf16 At[64][264];   // +8 pad -> 2-way LDS conflicts only
    int t = threadIdx.x;
    int base = blockIdx.x * 64;
    int wave = t >> 6, lane = t & 63;
#pragma unroll 1
    for (int rr = 0; rr < 16; rr++) {
        int row = wave * 16 + rr;
        int rg = base + row;
        float a0 = 0.f, a1 = 0.f, a2 = 0.f, a3 = 0.f;
        int dg = 0;
        if (rg < N3) {
            dg = cntN[IC2 + rg];
            int off = offsN[IC2 + rg];
            for (int cb = 0; cb < dg; cb += 64) {
                int rem = dg - cb; if (rem > 64) rem = 64;
                int s_all = (lane < rem) ? pool[off + cb + lane] : 0;
                int i = 0;
                for (; i + 4 <= rem; i += 4) {
                    int s0 = __shfl(s_all, i,     64);
                    int s1 = __shfl(s_all, i + 1, 64);
                    int s2 = __shfl(s_all, i + 2, 64);
                    int s3 = __shfl(s_all, i + 3, 64);
                    union { ushort4 u; __bf16 b[4]; } v0, v1, v2, v3;
                    v0.u = *(const ushort4*)(h2b + (size_t)s0 * 256 + lane * 4);
                    v1.u = *(const ushort4*)(h2b + (size_t)s1 * 256 + lane * 4);
                    v2.u = *(const ushort4*)(h2b + (size_t)s2 * 256 + lane * 4);
                    v3.u = *(const ushort4*)(h2b + (size_t)s3 * 256 + lane * 4);
                    a0 += ((float)v0.b[0] + (float)v1.b[0]) + ((float)v2.b[0] + (float)v3.b[0]);
                    a1 += ((float)v0.b[1] + (float)v1.b[1]) + ((float)v2.b[1] + (float)v3.b[1]);
                    a2 += ((float)v0.b[2] + (float)v1.b[2]) + ((float)v2.b[2] + (float)v3.b[2]);
                    a3 += ((float)v0.b[3] + (float)v1.b[3]) + ((float)v2.b[3] + (float)v3.b[3]);
                }
                for (; i < rem; i++) {
                    int s0 = __shfl(s_all, i, 64);
                    union { ushort4 u; __bf16 b[4]; } v0;
                    v0.u = *(const ushort4*)(h2b + (size_t)s0 * 256 + lane * 4);
                    a0 += (float)v0.b[0]; a1 += (float)v0.b[1];
                    a2 += (float)v0.b[2]; a3 += (float)v0.b[3];
                }
            }
        }
        float sc = rsqrtf(fmaxf((float)dg, 1.0f));
        union { __bf16 b[4]; uint2 u; } cv;
        cv.b[0] = (__bf16)(a0 * sc); cv.b[1] = (__bf16)(a1 * sc);
        cv.b[2] = (__bf16)(a2 * sc); cv.b[3] = (__bf16)(a3 * sc);
        *(uint2*)&At[row][lane * 4] = cv.u;
    }
    __syncthreads();
    int q = lane >> 4, r16 = lane & 15;
    f32x4 acc[4][4] = {};
    for (int ks = 0; ks < 8; ks++) {
        bf16x8 a[4], b[4];
        int ko = ks * 32 + q * 8;
#pragma unroll
        for (int mt = 0; mt < 4; mt++)
            a[mt] = *(const bf16x8*)&At[mt * 16 + r16][ko];
#pragma unroll
        for (int i = 0; i < 4; i++) {
            int tn = wave * 4 + i;
            b[i] = *(const bf16x8*)&W2p[((size_t)(tn * 8 + ks) * 64 + lane) * 8];
        }
#pragma unroll
        for (int mt = 0; mt < 4; mt++)
#pragma unroll
            for (int i = 0; i < 4; i++)
                acc[mt][i] = __builtin_amdgcn_mfma_f32_16x16x32_bf16(a[mt], b[i], acc[mt][i], 0, 0, 0);
    }
#pragma unroll
    for (int mt = 0; mt < 4; mt++) {
#pragma unroll
        for (int i = 0; i < 4; i++) {
            int col = (wave * 4 + i) * 16 + r16;
            float bb = b2v[col];
#pragma unroll
            for (int rr = 0; rr < 4; rr++) {
                int row = base + mt * 16 + q * 4 + rr;
                if (row < N3)
                    x3b[(size_t)row * 256 + col] = (__bf16)fmaxf(acc[mt][i][rr] + bb, 0.0f);
            }
        }
    }
}

// ---------------- final via MFMA: out = [x3b[ss], x3b[sd]] @ Wfc + bfc ----------------
__global__ __launch_bounds__(256) void k_final_mfma(const int* __restrict__ ss, const int* __restrict__ sd,
                                                    const __bf16* __restrict__ x3b,
                                                    const __bf16* __restrict__ Wp,
                                                    const float* __restrict__ bfc,
                                                    float* __restrict__ out) {
    __shared__ __bf16 At[64][520];   // +8 pad -> 2-way LDS conflicts only
    __shared__ int eidx[128];
    int t = threadIdx.x;
    int base = blockIdx.x * 64;
    if (t < 64)       { int e = base + t;      eidx[t] = ss[e < ESUB ? e : ESUB - 1]; }
    else if (t < 128) { int e = base + t - 64; eidx[t] = sd[e < ESUB ? e : ESUB - 1]; }
    __syncthreads();
#pragma unroll
    for (int it = 0; it < 16; it++) {
        int c = it * 256 + t;       // 0..4095
        int row = c >> 6;           // 0..63
        int cpos = c & 63;          // 16B chunk within 512-elem row
        int half = cpos >> 5;
        int off8 = (cpos & 31) * 8;
        int node = eidx[half * 64 + row];
        uint4 v = *(const uint4*)(x3b + (size_t)node * 256 + off8);
        *(uint4*)&At[row][half * 256 + off8] = v;
    }
    __syncthreads();
    int wave = t >> 6, lane = t & 63;
    int q = lane >> 4, r16 = lane & 15;
    f32x4 acc[4][4] = {};
    for (int ks = 0; ks < 16; ks++) {
        bf16x8 a[4], b[4];
        int ko = ks * 32 + q * 8;
#pragma unroll
        for (int mt = 0; mt < 4; mt++)
            a[mt] = *(const bf16x8*)&At[mt * 16 + r16][ko];
#pragma unroll
        for (int i = 0; i < 4; i++) {
            int tn = wave * 4 + i;
            b[i] = *(const bf16x8*)&Wp[((size_t)(tn * 16 + ks) * 64 + lane) * 8];
        }
#pragma unroll
        for (int mt = 0; mt < 4; mt++)
#pragma unroll
            for (int i = 0; i < 4; i++)
                acc[mt][i] = __builtin_amdgcn_mfma_f32_16x16x32_bf16(a[mt], b[i], acc[mt][i], 0, 0, 0);
    }
#pragma unroll
    for (int mt = 0; mt < 4; mt++) {
#pragma unroll
        for (int i = 0; i < 4; i++) {
            int col = (wave * 4 + i) * 16 + r16;
            float bb = bfc[col];
#pragma unroll
            for (int rr = 0; rr < 4; rr++) {
                int row = base + mt * 16 + q * 4 + rr;
                if (row < ESUB)
                    out[(size_t)row * 256 + col] = acc[mt][i][rr] + bb;
            }
        }
    }
}

extern "C" void kernel_launch(void* const* d_in, const int* in_sizes, int n_in,
                              void* d_out, int out_size, void* d_ws, size_t ws_size,
                              hipStream_t stream) {
    const int* e0_type = (const int*)d_in[0];
    const int* e0_src  = (const int*)d_in[1];
    const int* e0_dst  = (const int*)d_in[2];
    const int* e1_src  = (const int*)d_in[3];
    const int* e1_dst  = (const int*)d_in[4];
    const int* e2_src  = (const int*)d_in[5];
    const int* e2_dst  = (const int*)d_in[6];
    const int* sub_src = (const int*)d_in[7];
    const int* sub_dst = (const int*)d_in[8];
    const float* rel_emb = (const float*)d_in[9];
    const float* W_out   = (const float*)d_in[10];
    const float* b_out   = (const float*)d_in[11];
    const float* W_in    = (const float*)d_in[12];
    const float* b_in    = (const float*)d_in[13];
    const float* W1      = (const float*)d_in[14];
    const float* b1      = (const float*)d_in[15];
    const float* W2      = (const float*)d_in[16];
    const float* b2v     = (const float*)d_in[17];
    const float* Wfc     = (const float*)d_in[18];
    const float* bfc     = (const float*)d_in[19];
    float* out = (float*)d_out;

    // ---- workspace layout (4-byte units), ~190 MB ----
    // zeroed: [bcnt(1024) | bcur(1024) | deg1o(N1) | deg2o(N2)]
    int* bcnt  = (int*)d_ws;
    int* bcur  = bcnt + 1024;
    int* deg1o = bcur + 1024;
    int* deg2o = deg1o + N1;
    // non-zeroed:
    int* boffs = deg2o + N2;             // NBALL+1
    int* cntN  = boffs + 1025;           // LALL
    int* offsN = cntN + LALL;            // LALL
    int* pool  = offsN + LALL;           // POOLCAP (node-sorted; e2 = pool[0..E2))
    int* cpool = pool + POOLCAP;         // POOLCAP (coarse)
    float* h1  = (float*)(cpool + POOLCAP);          // N1*64 f32
    __bf16* h2b = (__bf16*)(h1 + (size_t)N1 * 64);   // N2*256 bf16
    __bf16* Wfcp = (__bf16*)(h2b + (size_t)N2 * 256); // 512*256 bf16
    __bf16* W2p  = Wfcp + 131072;                    // 256*256 bf16
    // x3b aliases pool-after-e2 + cpool (both dead by conv2g)
    __bf16* x3b  = (__bf16*)(pool + E2);

    const int BT = 256;

    // zero counters (~1.1 MB contiguous)
    hipMemsetAsync(d_ws, 0, (size_t)(1024 + 1024 + N1 + N2) * sizeof(int), stream);

    // pack weights (independent of zeroed region)
    k_pack<<<512, BT, 0, stream>>>(Wfc, Wfcp, 16);
    k_pack<<<256, BT, 0, stream>>>(W2, W2p, 8);

    // bucket counting (+ out-degrees for e1/e2)
    int nbA0 = (E0 + BINCHUNK - 1) / BINCHUNK;
    int nbA1 = (E1 + BINCHUNK - 1) / BINCHUNK;
    int nbA2 = (E2 + BINCHUNK - 1) / BINCHUNK;
    k_cntb0<<<nbA0, BT, 0, stream>>>(e0_src, e0_dst, bcnt);
    k_cnt2b<<<nbA1, BT, 0, stream>>>(e1_src, e1_dst, E1, deg1o, bcnt, CB1);
    k_cnt2b<<<nbA2, BT, 0, stream>>>(e2_src, e2_dst, E2, deg2o, bcnt, CB2);

    // bucket scan
    k_bscanA<<<1, BT, 0, stream>>>(bcnt, boffs);

    // pass A: dense coarse binning
    k_binA<<<nbA2, BT, 0, stream>>>(e2_dst, e2_src, E2, boffs, bcur, CB2, cpool);
    k_binA0b<<<nbA0, BT, 0, stream>>>(e0_type, e0_src, e0_dst, boffs, bcur, cpool);
    k_binA<<<nbA1, BT, 0, stream>>>(e1_dst, e1_src, E1, boffs, bcur, CB1, cpool);

    // pass B: node-sort within buckets + emit per-node CSR (cntN/offsN)
    k_binBall<<<NBALL, BT, 0, stream>>>(boffs, cpool, pool, cntN, offsN);

    // layer 0 -> h1
    k_layer0<<<N1 / 4, BT, 0, stream>>>(cntN, offsN, pool, rel_emb, W_out, b_out, W_in, b_in, deg1o, h1);

    // conv1 (fused gather) -> h2 (bf16)
    k_conv1g<<<N2 / 8, BT, 0, stream>>>(h1, cntN, offsN, pool, deg2o, W1, b1, h2b);

    // conv2 (fused gather, MFMA) -> x3b
    k_conv2g<<<(N3 + 63) / 64, BT, 0, stream>>>(h2b, cntN, offsN, pool, W2p, b2v, x3b);

    // final edge MLP (MFMA)
    k_final_mfma<<<(ESUB + 63) / 64, BT, 0, stream>>>(sub_src, sub_dst, x3b, Wfcp, bfc, out);
}

// Round 6
// 954.920 us; speedup vs baseline: 2.1742x; 1.0263x over previous
//
#include <hip/hip_runtime.h>
#include <hip/hip_bf16.h>

#define N0 200000
#define N1 150000
#define N2 120000
#define N3 100000
#define E0 2000000
#define E1 1000000
#define E2 500000
#define ESUB 250000

// per-node CSR arrays (cntN/offsN) layout: [c2 | c1 | c0s | c0d]
#define IC2 0
#define IC1 N3
#define I0S (N3 + N2)
#define I0D (N3 + N2 + N1)
#define LALL (N3 + N2 + 2 * N1)     // 520000

// coarse buckets: 512 nodes per bucket (node >> 9), order [B2 | B1 | B0S | B0D]
#define NC2  ((N3 + 511) / 512)      // 196
#define NC1  ((N2 + 511) / 512)      // 235
#define NC0B ((N1 + 511) / 512)      // 293
#define CB2  0
#define CB1  NC2
#define CB0S (NC2 + NC1)             // 431
#define CB0D (NC2 + NC1 + NC0B)      // 724
#define NBALL (NC2 + NC1 + 2 * NC0B) // 1017

#define BINCHUNK 4096
#define POOLCAP (E2 + E1 + 2 * E0)   // 5,500,000 upper bound

typedef float f32x4 __attribute__((ext_vector_type(4)));
typedef __bf16 bf16x8 __attribute__((ext_vector_type(8)));

// ---------------- REW precompute: REW[side][ty][k] = (rel_emb @ W_side)[ty][k] ----------------
__global__ __launch_bounds__(256) void k_rew(const float* __restrict__ rel_emb,
                                             const float* __restrict__ W_out,
                                             const float* __restrict__ W_in,
                                             float* __restrict__ REW) {
    int idx = blockIdx.x * 256 + threadIdx.x;
    if (idx >= 32000) return;
    int side = idx / 16000;
    int rest = idx - side * 16000;
    int ty = rest >> 5, k = rest & 31;
    const float* W = side ? W_in : W_out;
    float s = 0.f;
#pragma unroll
    for (int j = 0; j < 32; j++) s += rel_emb[ty * 32 + j] * W[j * 32 + k];
    REW[idx] = s;
}

// ---------------- bucket counting: e0 both sides ----------------
__global__ __launch_bounds__(256) void k_cntb0(const int* __restrict__ src, const int* __restrict__ dst,
                                               int* __restrict__ bcnt) {
    __shared__ int lcnt[1024];
    int t = threadIdx.x;
#pragma unroll
    for (int j = 0; j < 4; j++) lcnt[t + j * 256] = 0;
    __syncthreads();
    int e0 = blockIdx.x * BINCHUNK;
    int e1 = E0 - e0; if (e1 > BINCHUNK) e1 = BINCHUNK; e1 += e0;
    for (int i = e0 + t; i < e1; i += 256) {
        int s = src[i];
        if (s < N1) atomicAdd(&lcnt[s >> 9], 1);
        atomicAdd(&lcnt[512 + (dst[i] >> 9)], 1);
    }
    __syncthreads();
    for (int b = t; b < 1024; b += 256) {
        int c = lcnt[b];
        if (c > 0) atomicAdd(&bcnt[(b >= 512 ? CB0D - 512 : CB0S) + b], c);
    }
}

// ---------------- bucket counting e1/e2 + out-degree ----------------
__global__ __launch_bounds__(256) void k_cnt2b(const int* __restrict__ src, const int* __restrict__ dst,
                                               int n, int* __restrict__ dego,
                                               int* __restrict__ bcnt, int bbase) {
    __shared__ int lcnt[512];
    int t = threadIdx.x;
    lcnt[t] = 0; lcnt[t + 256] = 0;
    __syncthreads();
    int e0 = blockIdx.x * BINCHUNK;
    int e1 = n - e0; if (e1 > BINCHUNK) e1 = BINCHUNK; e1 += e0;
    for (int i = e0 + t; i < e1; i += 256) {
        atomicAdd(&dego[src[i]], 1);
        atomicAdd(&lcnt[dst[i] >> 9], 1);
    }
    __syncthreads();
    for (int b = t; b < 512; b += 256) {
        int c = lcnt[b];
        if (c > 0) atomicAdd(&bcnt[bbase + b], c);
    }
}

// ---------------- scan of 1017 bucket counts -> boffs[1018] (single block) ----------------
__global__ __launch_bounds__(256) void k_bscanA(const int* __restrict__ bcnt, int* __restrict__ boffs) {
    __shared__ int A[1024], B[1024];
    int t = threadIdx.x;
    for (int i = t; i < 1024; i += 256) A[i] = (i < NBALL) ? bcnt[i] : 0;
    __syncthreads();
    int* cur = A; int* nxt = B;
    for (int off = 1; off < 1024; off <<= 1) {
        for (int i = t; i < 1024; i += 256) nxt[i] = cur[i] + (i >= off ? cur[i - off] : 0);
        __syncthreads();
        int* tmp = cur; cur = nxt; nxt = tmp;
    }
    for (int i = t; i < NBALL; i += 256) boffs[i + 1] = cur[i];
    if (t == 0) boffs[0] = 0;
}

// ---------------- pass A (e1/e2): dense coarse runs at bucket offsets ----------------
// Entry packs (node & 511) << 18 | payload (payload < 2^18).
__global__ __launch_bounds__(256) void k_binA(const int* __restrict__ dst, const int* __restrict__ aux,
                                              int n, const int* __restrict__ boffs,
                                              int* __restrict__ bcur, int ccbase,
                                              int* __restrict__ cpool) {
    __shared__ int lcnt[512], lbase[512], lcur[512];
    int t = threadIdx.x;
    lcnt[t] = 0; lcnt[t + 256] = 0;
    lcur[t] = 0; lcur[t + 256] = 0;
    __syncthreads();
    int e0 = blockIdx.x * BINCHUNK;
    int e1 = n - e0; if (e1 > BINCHUNK) e1 = BINCHUNK; e1 += e0;
    for (int i = e0 + t; i < e1; i += 256) {
        atomicAdd(&lcnt[dst[i] >> 9], 1);
    }
    __syncthreads();
    for (int b = t; b < 512; b += 256) {
        int c = lcnt[b];
        if (c > 0) lbase[b] = boffs[ccbase + b] + atomicAdd(&bcur[ccbase + b], c);
    }
    __syncthreads();
    for (int i = e0 + t; i < e1; i += 256) {
        int d = dst[i];
        int b = d >> 9;
        int r = atomicAdd(&lcur[b], 1);
        cpool[lbase[b] + r] = ((d & 511) << 18) | aux[i];
    }
}

// ---------------- pass A (e0): both sides in one read ----------------
__global__ __launch_bounds__(256) void k_binA0b(const int* __restrict__ typ,
                                                const int* __restrict__ src, const int* __restrict__ dst,
                                                const int* __restrict__ boffs,
                                                int* __restrict__ bcur, int* __restrict__ cpool) {
    __shared__ int lcnt[1024], lbase[1024], lcur[1024];
    int t = threadIdx.x;
#pragma unroll
    for (int j = 0; j < 4; j++) { lcnt[t + j * 256] = 0; lcur[t + j * 256] = 0; }
    __syncthreads();
    int e0 = blockIdx.x * BINCHUNK;
    int e1 = E0 - e0; if (e1 > BINCHUNK) e1 = BINCHUNK; e1 += e0;
    for (int i = e0 + t; i < e1; i += 256) {
        int s = src[i];
        if (s < N1) atomicAdd(&lcnt[s >> 9], 1);
        atomicAdd(&lcnt[512 + (dst[i] >> 9)], 1);
    }
    __syncthreads();
    for (int b = t; b < 1024; b += 256) {
        int c = lcnt[b];
        if (c > 0) {
            int idx = (b >= 512 ? CB0D - 512 : CB0S) + b;
            lbase[b] = boffs[idx] + atomicAdd(&bcur[idx], c);
        }
    }
    __syncthreads();
    for (int i = e0 + t; i < e1; i += 256) {
        int ty = typ[i];
        int s = src[i];
        if (s < N1) {
            int b = s >> 9;
            int r = atomicAdd(&lcur[b], 1);
            cpool[lbase[b] + r] = ((s & 511) << 18) | ty;
        }
        int d = dst[i];
        int b2 = 512 + (d >> 9);
        int r2 = atomicAdd(&lcur[b2], 1);
        cpool[lbase[b2] + r2] = ((d & 511) << 18) | ty;
    }
}

// ---------------- pass B (all graphs): coarse region -> node-sorted pool + per-node CSR ----------------
__global__ __launch_bounds__(256) void k_binBall(const int* __restrict__ boffs,
                                                 const int* __restrict__ cpool,
                                                 int* __restrict__ pool,
                                                 int* __restrict__ cntN, int* __restrict__ offsN) {
    __shared__ int lcnt[512], lexc[512];
    int t = threadIdx.x;
    int g = blockIdx.x;
    int cbase, n0, nseg;
    if (g < CB1)       { cbase = IC2; n0 = g << 9;            nseg = N3; }
    else if (g < CB0S) { cbase = IC1; n0 = (g - CB1) << 9;    nseg = N2; }
    else if (g < CB0D) { cbase = I0S; n0 = (g - CB0S) << 9;   nseg = N1; }
    else               { cbase = I0D; n0 = (g - CB0D) << 9;   nseg = N1; }
    int nodes = nseg - n0; if (nodes > 512) nodes = 512;
    lcnt[t] = 0; lcnt[t + 256] = 0;
    __syncthreads();
    int R0 = boffs[g], R1 = boffs[g + 1];
    // pass 1: per-node counts
    for (int i = R0 + t; i < R1; i += 256) atomicAdd(&lcnt[cpool[i] >> 18], 1);
    __syncthreads();
    // inclusive scan of lcnt into lexc (512 entries, 2 per thread, Hillis-Steele)
    lexc[t] = lcnt[t]; lexc[t + 256] = lcnt[t + 256];
    __syncthreads();
    for (int off = 1; off < 512; off <<= 1) {
        int a0 = (t >= off) ? lexc[t - off] : 0;
        int a1 = (t + 256 >= off) ? lexc[t + 256 - off] : 0;
        __syncthreads();
        lexc[t] += a0; lexc[t + 256] += a1;
        __syncthreads();
    }
    // emit per-node CSR; convert lexc to exclusive; reset lcnt as cursor
#pragma unroll
    for (int jj = 0; jj < 2; jj++) {
        int j = t + jj * 256;
        int c = lcnt[j];
        int ex = lexc[j] - c;
        if (j < nodes) { cntN[cbase + n0 + j] = c; offsN[cbase + n0 + j] = R0 + ex; }
        lexc[j] = ex; lcnt[j] = 0;
    }
    __syncthreads();
    // pass 2: scatter payload into node-sorted slots (window L2-dense)
    for (int i = R0 + t; i < R1; i += 256) {
        int p = cpool[i];
        int low = p >> 18;
        int r = atomicAdd(&lcnt[low], 1);
        pool[R0 + lexc[low] + r] = p & 0x3FFFF;
    }
}

// ---------------- layer 0: pure REW gather-sum -> h1 (bf16). No LDS, no sync. ----------------
__global__ __launch_bounds__(256) void k_layer0r(const int* __restrict__ cntN, const int* __restrict__ offsN,
                                                 const int* __restrict__ pool, const float* __restrict__ REW,
                                                 const float* __restrict__ b_out, const float* __restrict__ b_in,
                                                 const int* __restrict__ deg1o, __bf16* __restrict__ h1b) {
    int t = threadIdx.x;
    int nl = t >> 6;
    int lane = t & 63;
    int half = lane >> 5;   // 0 = out(src-agg), 1 = in(dst-agg)
    int k = lane & 31;
    int n = blockIdx.x * 4 + nl;        // grid exact: N1 % 4 == 0
    int ci = (half ? I0D : I0S) + n;
    int dg = cntN[ci];
    int off = offsN[ci];
    const float* R = REW + half * 16000;
    float acc = 0.0f;
    for (int cb = 0; cb < dg; cb += 32) {
        int rem = dg - cb; if (rem > 32) rem = 32;
        int ty_all = (k < rem) ? pool[off + cb + k] : 0;
        int i2 = 0;
        for (; i2 + 4 <= rem; i2 += 4) {
            int t0 = __shfl(ty_all, i2,     32);
            int t1 = __shfl(ty_all, i2 + 1, 32);
            int t2 = __shfl(ty_all, i2 + 2, 32);
            int t3 = __shfl(ty_all, i2 + 3, 32);
            float a0 = R[t0 * 32 + k];
            float a1 = R[t1 * 32 + k];
            float a2 = R[t2 * 32 + k];
            float a3 = R[t3 * 32 + k];
            acc += a0; acc += a1; acc += a2; acc += a3;
        }
        for (; i2 < rem; i2++) {
            int ty = __shfl(ty_all, i2, 32);
            acc += R[ty * 32 + k];
        }
    }
    float b = half ? b_in[k] : b_out[k];
    float r = (dg > 0) ? (acc / (float)dg + b) : 0.0f;
    h1b[(size_t)n * 64 + lane] = (__bf16)(r * rsqrtf(fmaxf((float)deg1o[n], 1.0f)));
}

// ---------------- conv1 with fused gather: bf16 h1, 2 edges per wave-step ----------------
__global__ __launch_bounds__(256) void k_conv1g(const __bf16* __restrict__ h1b,
                                                const int* __restrict__ cntN, const int* __restrict__ offsN,
                                                const int* __restrict__ pool, const int* __restrict__ deg2o,
                                                const float* __restrict__ W1, const float* __restrict__ b1,
                                                __bf16* __restrict__ h2b) {
    __shared__ float row[8][64];
    int base = blockIdx.x * 8;
    int t = threadIdx.x;
    int wave = t >> 6, lane = t & 63;
    int eo = lane >> 5;      // which of the 2 concurrent edges this lane serves
    int c = lane & 31;       // uint column (covers bf16 cols 2c, 2c+1)
#pragma unroll
    for (int rr = 0; rr < 2; rr++) {
        int m = wave * 2 + rr;
        int rg = base + m;                       // grid exact: rg < N2
        int dg = cntN[IC1 + rg];
        int off = offsN[IC1 + rg];
        float a0 = 0.f, a1 = 0.f;
        for (int cb = 0; cb < dg; cb += 64) {
            int rem = dg - cb; if (rem > 64) rem = 64;
            int s_all = (lane < rem) ? pool[off + cb + lane] : 0;
            int i = 0;
            for (; i + 8 <= rem; i += 8) {
                int sA = __shfl(s_all, i     + eo, 64);
                int sB = __shfl(s_all, i + 2 + eo, 64);
                int sC = __shfl(s_all, i + 4 + eo, 64);
                int sD = __shfl(s_all, i + 6 + eo, 64);
                union { unsigned u; __bf16 b[2]; } vA, vB, vC, vD;
                vA.u = *(const unsigned*)(h1b + (size_t)sA * 64 + c * 2);
                vB.u = *(const unsigned*)(h1b + (size_t)sB * 64 + c * 2);
                vC.u = *(const unsigned*)(h1b + (size_t)sC * 64 + c * 2);
                vD.u = *(const unsigned*)(h1b + (size_t)sD * 64 + c * 2);
                a0 += ((float)vA.b[0] + (float)vB.b[0]) + ((float)vC.b[0] + (float)vD.b[0]);
                a1 += ((float)vA.b[1] + (float)vB.b[1]) + ((float)vC.b[1] + (float)vD.b[1]);
            }
            for (; i < rem; i += 2) {
                int have = rem - i;              // 1 or 2
                int s = __shfl(s_all, i + ((eo < have) ? eo : 0), 64);
                union { unsigned u; __bf16 b[2]; } v;
                v.u = *(const unsigned*)(h1b + (size_t)s * 64 + c * 2);
                if (eo < have) { a0 += (float)v.b[0]; a1 += (float)v.b[1]; }
            }
        }
        a0 += __shfl_xor(a0, 32, 64);
        a1 += __shfl_xor(a1, 32, 64);
        if (eo == 0) {
            float sc = rsqrtf(fmaxf((float)dg, 1.0f));
            row[m][c * 2]     = a0 * sc;
            row[m][c * 2 + 1] = a1 * sc;
        }
    }
    __syncthreads();
    float acc8[8] = {0, 0, 0, 0, 0, 0, 0, 0};
    for (int k = 0; k < 64; k++) {
        float w = W1[k * 256 + t];
#pragma unroll
        for (int m = 0; m < 8; m++) acc8[m] += row[m][k] * w;
    }
    float bb = b1[t];
#pragma unroll
    for (int m = 0; m < 8; m++) {
        float v = fmaxf(acc8[m] + bb, 0.0f) * rsqrtf(fmaxf((float)deg2o[base + m], 1.0f));
        h2b[(size_t)(base + m) * 256 + t] = (__bf16)v;
    }
}

// ---------------- pack W (K x 256 f32, row-major) into MFMA B-fragment order (bf16) ----------------
__global__ void k_pack(const float* __restrict__ W, __bf16* __restrict__ Wp, int ksteps) {
    int idx = blockIdx.x * 256 + threadIdx.x;
    int j = idx & 7;
    int lane = (idx >> 3) & 63;
    int rest = idx >> 9;
    int ks = rest % ksteps;
    int tn = rest / ksteps;
    int k = ks * 32 + ((lane >> 4) * 8) + j;
    int n = tn * 16 + (lane & 15);
    Wp[idx] = (__bf16)W[k * 256 + n];
}

// ---------------- conv2 MFMA with fused gather (bf16 h2, unroll x4) ----------------
__global__ __launch_bounds__(256) void k_conv2g(const __bf16* __restrict__ h2b,
                                                const int* __restrict__ cntN, const int* __restrict__ offsN,
                                                const int* __restrict__ pool,
                                                const __bf16* __restrict__ W2p,
                                                const float* __restrict__ b2v,
                                                __bf16* __restrict__ x3b) {
    __shared__ __bf16 At[64][264];   // +8 pad -> 2-way LDS conflicts only
    int t = threadIdx.x;
    int base = blockIdx.x * 64;
    int wave = t >> 6, lane = t & 63;
#pragma unroll 1
    for (int rr = 0; rr < 16; rr++) {
        int row = wave * 16 + rr;
        int rg = base + row;
        float a0 = 0.f, a1 = 0.f, a2 = 0.f, a3 = 0.f;
        int dg = 0;
        if (rg < N3) {
            dg = cntN[IC2 + rg];
            int off = offsN[IC2 + rg];
            for (int cb = 0; cb < dg; cb += 64) {
                int rem = dg - cb; if (rem > 64) rem = 64;
                int s_all = (lane < rem) ? pool[off + cb + lane] : 0;
                int i = 0;
                for (; i + 4 <= rem; i += 4) {
                    int s0 = __shfl(s_all, i,     64);
                    int s1 = __shfl(s_all, i + 1, 64);
                    int s2 = __shfl(s_all, i + 2, 64);
                    int s3 = __shfl(s_all, i + 3, 64);
                    union { ushort4 u; __bf16 b[4]; } v0, v1, v2, v3;
                    v0.u = *(const ushort4*)(h2b + (size_t)s0 * 256 + lane * 4);
                    v1.u = *(const ushort4*)(h2b + (size_t)s1 * 256 + lane * 4);
                    v2.u = *(const ushort4*)(h2b + (size_t)s2 * 256 + lane * 4);
                    v3.u = *(const ushort4*)(h2b + (size_t)s3 * 256 + lane * 4);
                    a0 += ((float)v0.b[0] + (float)v1.b[0]) + ((float)v2.b[0] + (float)v3.b[0]);
                    a1 += ((float)v0.b[1] + (float)v1.b[1]) + ((float)v2.b[1] + (float)v3.b[1]);
                    a2 += ((float)v0.b[2] + (float)v1.b[2]) + ((float)v2.b[2] + (float)v3.b[2]);
                    a3 += ((float)v0.b[3] + (float)v1.b[3]) + ((float)v2.b[3] + (float)v3.b[3]);
                }
                for (; i < rem; i++) {
                    int s0 = __shfl(s_all, i, 64);
                    union { ushort4 u; __bf16 b[4]; } v0;
                    v0.u = *(const ushort4*)(h2b + (size_t)s0 * 256 + lane * 4);
                    a0 += (float)v0.b[0]; a1 += (float)v0.b[1];
                    a2 += (float)v0.b[2]; a3 += (float)v0.b[3];
                }
            }
        }
        float sc = rsqrtf(fmaxf((float)dg, 1.0f));
        union { __bf16 b[4]; uint2 u; } cv;
        cv.b[0] = (__bf16)(a0 * sc); cv.b[1] = (__bf16)(a1 * sc);
        cv.b[2] = (__bf16)(a2 * sc); cv.b[3] = (__bf16)(a3 * sc);
        *(uint2*)&At[row][lane * 4] = cv.u;
    }
    __syncthreads();
    int q = lane >> 4, r16 = lane & 15;
    f32x4 acc[4][4] = {};
    for (int ks = 0; ks < 8; ks++) {
        bf16x8 a[4], b[4];
        int ko = ks * 32 + q * 8;
#pragma unroll
        for (int mt = 0; mt < 4; mt++)
            a[mt] = *(const bf16x8*)&At[mt * 16 + r16][ko];
#pragma unroll
        for (int i = 0; i < 4; i++) {
            int tn = wave * 4 + i;
            b[i] = *(const bf16x8*)&W2p[((size_t)(tn * 8 + ks) * 64 + lane) * 8];
        }
#pragma unroll
        for (int mt = 0; mt < 4; mt++)
#pragma unroll
            for (int i = 0; i < 4; i++)
                acc[mt][i] = __builtin_amdgcn_mfma_f32_16x16x32_bf16(a[mt], b[i], acc[mt][i], 0, 0, 0);
    }
#pragma unroll
    for (int mt = 0; mt < 4; mt++) {
#pragma unroll
        for (int i = 0; i < 4; i++) {
            int col = (wave * 4 + i) * 16 + r16;
            float bb = b2v[col];
#pragma unroll
            for (int rr = 0; rr < 4; rr++) {
                int row = base + mt * 16 + q * 4 + rr;
                if (row < N3)
                    x3b[(size_t)row * 256 + col] = (__bf16)fmaxf(acc[mt][i][rr] + bb, 0.0f);
            }
        }
    }
}

// ---------------- final via MFMA: out = [x3b[ss], x3b[sd]] @ Wfc + bfc ----------------
__global__ __launch_bounds__(256) void k_final_mfma(const int* __restrict__ ss, const int* __restrict__ sd,
                                                    const __bf16* __restrict__ x3b,
                                                    const __bf16* __restrict__ Wp,
                                                    const float* __restrict__ bfc,
                                                    float* __restrict__ out) {
    __shared__ __bf16 At[64][520];   // +8 pad -> 2-way LDS conflicts only
    __shared__ int eidx[128];
    int t = threadIdx.x;
    int base = blockIdx.x * 64;
    if (t < 64)       { int e = base + t;      eidx[t] = ss[e < ESUB ? e : ESUB - 1]; }
    else if (t < 128) { int e = base + t - 64; eidx[t] = sd[e < ESUB ? e : ESUB - 1]; }
    __syncthreads();
#pragma unroll
    for (int it = 0; it < 16; it++) {
        int c = it * 256 + t;       // 0..4095
        int row = c >> 6;           // 0..63
        int cpos = c & 63;          // 16B chunk within 512-elem row
        int half = cpos >> 5;
        int off8 = (cpos & 31) * 8;
        int node = eidx[half * 64 + row];
        uint4 v = *(const uint4*)(x3b + (size_t)node * 256 + off8);
        *(uint4*)&At[row][half * 256 + off8] = v;
    }
    __syncthreads();
    int wave = t >> 6, lane = t & 63;
    int q = lane >> 4, r16 = lane & 15;
    f32x4 acc[4][4] = {};
    for (int ks = 0; ks < 16; ks++) {
        bf16x8 a[4], b[4];
        int ko = ks * 32 + q * 8;
#pragma unroll
        for (int mt = 0; mt < 4; mt++)
            a[mt] = *(const bf16x8*)&At[mt * 16 + r16][ko];
#pragma unroll
        for (int i = 0; i < 4; i++) {
            int tn = wave * 4 + i;
            b[i] = *(const bf16x8*)&Wp[((size_t)(tn * 16 + ks) * 64 + lane) * 8];
        }
#pragma unroll
        for (int mt = 0; mt < 4; mt++)
#pragma unroll
            for (int i = 0; i < 4; i++)
                acc[mt][i] = __builtin_amdgcn_mfma_f32_16x16x32_bf16(a[mt], b[i], acc[mt][i], 0, 0, 0);
    }
#pragma unroll
    for (int mt = 0; mt < 4; mt++) {
#pragma unroll
        for (int i = 0; i < 4; i++) {
            int col = (wave * 4 + i) * 16 + r16;
            float bb = bfc[col];
#pragma unroll
            for (int rr = 0; rr < 4; rr++) {
                int row = base + mt * 16 + q * 4 + rr;
                if (row < ESUB)
                    out[(size_t)row * 256 + col] = acc[mt][i][rr] + bb;
            }
        }
    }
}

extern "C" void kernel_launch(void* const* d_in, const int* in_sizes, int n_in,
                              void* d_out, int out_size, void* d_ws, size_t ws_size,
                              hipStream_t stream) {
    const int* e0_type = (const int*)d_in[0];
    const int* e0_src  = (const int*)d_in[1];
    const int* e0_dst  = (const int*)d_in[2];
    const int* e1_src  = (const int*)d_in[3];
    const int* e1_dst  = (const int*)d_in[4];
    const int* e2_src  = (const int*)d_in[5];
    const int* e2_dst  = (const int*)d_in[6];
    const int* sub_src = (const int*)d_in[7];
    const int* sub_dst = (const int*)d_in[8];
    const float* rel_emb = (const float*)d_in[9];
    const float* W_out   = (const float*)d_in[10];
    const float* b_out   = (const float*)d_in[11];
    const float* W_in    = (const float*)d_in[12];
    const float* b_in    = (const float*)d_in[13];
    const float* W1      = (const float*)d_in[14];
    const float* b1      = (const float*)d_in[15];
    const float* W2      = (const float*)d_in[16];
    const float* b2v     = (const float*)d_in[17];
    const float* Wfc     = (const float*)d_in[18];
    const float* bfc     = (const float*)d_in[19];
    float* out = (float*)d_out;

    // ---- workspace layout (4-byte units) ----
    // zeroed: [bcnt(1024) | bcur(1024) | deg1o(N1) | deg2o(N2)]
    int* bcnt  = (int*)d_ws;
    int* bcur  = bcnt + 1024;
    int* deg1o = bcur + 1024;
    int* deg2o = deg1o + N1;
    // non-zeroed:
    int* boffs = deg2o + N2;             // NBALL+1
    int* cntN  = boffs + 1025;           // LALL
    int* offsN = cntN + LALL;            // LALL
    float* REW = (float*)(offsN + LALL); // 2 x 500 x 32
    int* pool  = (int*)(REW + 32000);    // POOLCAP (node-sorted; e2 = pool[0..E2))
    int* cpool = pool + POOLCAP;         // POOLCAP (coarse)
    __bf16* h1b = (__bf16*)(cpool + POOLCAP);        // N1*64 bf16
    __bf16* h2b = h1b + (size_t)N1 * 64;             // N2*256 bf16
    __bf16* Wfcp = h2b + (size_t)N2 * 256;           // 512*256 bf16
    __bf16* W2p  = Wfcp + 131072;                    // 256*256 bf16
    // x3b aliases pool-after-e2 + cpool + h1b (all dead by conv2g); 51.2MB fits in 61.2MB
    __bf16* x3b  = (__bf16*)(pool + E2);

    const int BT = 256;

    // zero counters (~1.1 MB contiguous)
    hipMemsetAsync(d_ws, 0, (size_t)(1024 + 1024 + N1 + N2) * sizeof(int), stream);

    // weight prep (independent of zeroed region)
    k_pack<<<512, BT, 0, stream>>>(Wfc, Wfcp, 16);
    k_pack<<<256, BT, 0, stream>>>(W2, W2p, 8);
    k_rew<<<125, BT, 0, stream>>>(rel_emb, W_out, W_in, REW);

    // bucket counting (+ out-degrees for e1/e2)
    int nbA0 = (E0 + BINCHUNK - 1) / BINCHUNK;
    int nbA1 = (E1 + BINCHUNK - 1) / BINCHUNK;
    int nbA2 = (E2 + BINCHUNK - 1) / BINCHUNK;
    k_cntb0<<<nbA0, BT, 0, stream>>>(e0_src, e0_dst, bcnt);
    k_cnt2b<<<nbA1, BT, 0, stream>>>(e1_src, e1_dst, E1, deg1o, bcnt, CB1);
    k_cnt2b<<<nbA2, BT, 0, stream>>>(e2_src, e2_dst, E2, deg2o, bcnt, CB2);

    // bucket scan
    k_bscanA<<<1, BT, 0, stream>>>(bcnt, boffs);

    // pass A: dense coarse binning
    k_binA<<<nbA2, BT, 0, stream>>>(e2_dst, e2_src, E2, boffs, bcur, CB2, cpool);
    k_binA0b<<<nbA0, BT, 0, stream>>>(e0_type, e0_src, e0_dst, boffs, bcur, cpool);
    k_binA<<<nbA1, BT, 0, stream>>>(e1_dst, e1_src, E1, boffs, bcur, CB1, cpool);

    // pass B: node-sort within buckets + emit per-node CSR (cntN/offsN)
    k_binBall<<<NBALL, BT, 0, stream>>>(boffs, cpool, pool, cntN, offsN);

    // layer 0 (REW gather-sum) -> h1 (bf16)
    k_layer0r<<<N1 / 4, BT, 0, stream>>>(cntN, offsN, pool, REW, b_out, b_in, deg1o, h1b);

    // conv1 (fused gather, bf16 h1) -> h2 (bf16)
    k_conv1g<<<N2 / 8, BT, 0, stream>>>(h1b, cntN, offsN, pool, deg2o, W1, b1, h2b);

    // conv2 (fused gather, MFMA) -> x3b
    k_conv2g<<<(N3 + 63) / 64, BT, 0, stream>>>(h2b, cntN, offsN, pool, W2p, b2v, x3b);

    // final edge MLP (MFMA)
    k_final_mfma<<<(ESUB + 63) / 64, BT, 0, stream>>>(sub_src, sub_dst, x3b, Wfcp, bfc, out);
}

// Round 7
// 861.213 us; speedup vs baseline: 2.4108x; 1.1088x over previous
//
#include <hip/hip_runtime.h>
#include <hip/hip_bf16.h>

#define N0 200000
#define N1 150000
#define N2 120000
#define N3 100000
#define E0 2000000
#define E1 1000000
#define E2 500000
#define ESUB 250000

// per-node CSR arrays (cntN/offsN) layout: [c2 | c1 | c0s | c0d]
#define IC2 0
#define IC1 N3
#define I0S (N3 + N2)
#define I0D (N3 + N2 + N1)
#define LALL (N3 + N2 + 2 * N1)     // 520000

// coarse buckets: 512 nodes per bucket (node >> 9), order [B2 | B1 | B0S | B0D]
#define NC2  ((N3 + 511) / 512)      // 196
#define NC1  ((N2 + 511) / 512)      // 235
#define NC0B ((N1 + 511) / 512)      // 293
#define CB2  0
#define CB1  NC2
#define CB0S (NC2 + NC1)             // 431
#define CB0D (NC2 + NC1 + NC0B)      // 724
#define NBALL (NC2 + NC1 + 2 * NC0B) // 1017

#define BINCHUNK 4096
#define SLAB 8192                    // fixed slab per bucket; max load ~6.8K (+16 sigma margin)
#define NBA0 ((E0 + BINCHUNK - 1) / BINCHUNK)   // 489
#define NBA1 ((E1 + BINCHUNK - 1) / BINCHUNK)   // 245
#define NBA2 ((E2 + BINCHUNK - 1) / BINCHUNK)   // 123

typedef float f32x4 __attribute__((ext_vector_type(4)));
typedef __bf16 bf16x8 __attribute__((ext_vector_type(8)));

// ---------------- REW precompute: REW[side][ty][k] = (rel_emb @ W_side)[ty][k] ----------------
__global__ __launch_bounds__(256) void k_rew(const float* __restrict__ rel_emb,
                                             const float* __restrict__ W_out,
                                             const float* __restrict__ W_in,
                                             float* __restrict__ REW) {
    int idx = blockIdx.x * 256 + threadIdx.x;
    if (idx >= 32000) return;
    int side = idx / 16000;
    int rest = idx - side * 16000;
    int ty = rest >> 5, k = rest & 31;
    const float* W = side ? W_in : W_out;
    float s = 0.f;
#pragma unroll
    for (int j = 0; j < 32; j++) s += rel_emb[ty * 32 + j] * W[j * 32 + k];
    REW[idx] = s;
}

// ---------------- unified pass A: slab-direct binning, all three edge lists ----------------
// Entry packs (node & 511) << 18 | payload (payload < 2^18).
// e0 blocks handle both sides (src<N1 filtered + dst) from one read; e1/e2 blocks
// additionally accumulate out-degree (dego) atomics fused into the write loop.
__global__ __launch_bounds__(256) void k_binAall(const int* __restrict__ typ,
                                                 const int* __restrict__ s0, const int* __restrict__ d0,
                                                 const int* __restrict__ s1, const int* __restrict__ d1,
                                                 const int* __restrict__ s2, const int* __restrict__ d2,
                                                 int* __restrict__ deg1o, int* __restrict__ deg2o,
                                                 int* __restrict__ bcnt, int* __restrict__ cpool) {
    __shared__ int lcnt[1024], lbase[1024], lcur[1024];
    int t = threadIdx.x;
    int blk = blockIdx.x;
    if (blk < NBA0) {
        // ---- e0: two-sided, 1024 local bins ----
#pragma unroll
        for (int j = 0; j < 4; j++) { lcnt[t + j * 256] = 0; lcur[t + j * 256] = 0; }
        __syncthreads();
        int eb = blk * BINCHUNK;
        int ee = E0 - eb; if (ee > BINCHUNK) ee = BINCHUNK; ee += eb;
        for (int i = eb + t; i < ee; i += 256) {
            int s = s0[i];
            if (s < N1) atomicAdd(&lcnt[s >> 9], 1);
            atomicAdd(&lcnt[512 + (d0[i] >> 9)], 1);
        }
        __syncthreads();
        for (int b = t; b < 1024; b += 256) {
            int c = lcnt[b];
            if (c > 0) {
                int idx = (b < 512) ? (CB0S + b) : (CB0D + (b - 512));
                lbase[b] = idx * SLAB + atomicAdd(&bcnt[idx], c);
            }
        }
        __syncthreads();
        for (int i = eb + t; i < ee; i += 256) {
            int ty = typ[i];
            int s = s0[i];
            if (s < N1) {
                int b = s >> 9;
                int r = atomicAdd(&lcur[b], 1);
                cpool[lbase[b] + r] = ((s & 511) << 18) | ty;
            }
            int d = d0[i];
            int b2 = 512 + (d >> 9);
            int r2 = atomicAdd(&lcur[b2], 1);
            cpool[lbase[b2] + r2] = ((d & 511) << 18) | ty;
        }
    } else {
        // ---- e1 or e2: single-sided, 512 bins, fused dego ----
        const int *dst, *aux; int n, gbase; int* dego;
        if (blk < NBA0 + NBA1) { dst = d1; aux = s1; n = E1; gbase = CB1; dego = deg1o; blk -= NBA0; }
        else                   { dst = d2; aux = s2; n = E2; gbase = CB2; dego = deg2o; blk -= NBA0 + NBA1; }
        lcnt[t] = 0; lcnt[t + 256] = 0;
        lcur[t] = 0; lcur[t + 256] = 0;
        __syncthreads();
        int eb = blk * BINCHUNK;
        int ee = n - eb; if (ee > BINCHUNK) ee = BINCHUNK; ee += eb;
        for (int i = eb + t; i < ee; i += 256) {
            atomicAdd(&lcnt[dst[i] >> 9], 1);
        }
        __syncthreads();
        for (int b = t; b < 512; b += 256) {
            int c = lcnt[b];
            if (c > 0) lbase[b] = (gbase + b) * SLAB + atomicAdd(&bcnt[gbase + b], c);
        }
        __syncthreads();
        for (int i = eb + t; i < ee; i += 256) {
            int d = dst[i];
            int a = aux[i];
            atomicAdd(&dego[a], 1);
            int b = d >> 9;
            int r = atomicAdd(&lcur[b], 1);
            cpool[lbase[b] + r] = ((d & 511) << 18) | a;
        }
    }
}

// ---------------- pass B: slab -> node-sorted pool + per-node CSR (single global read via LDS) ----------------
__global__ __launch_bounds__(256) void k_binBall(const int* __restrict__ bcnt,
                                                 const int* __restrict__ cpool,
                                                 int* __restrict__ pool,
                                                 int* __restrict__ cntN, int* __restrict__ offsN) {
    __shared__ int ent[SLAB];        // 32 KB
    __shared__ int lcnt[512], lexc[512];
    int t = threadIdx.x;
    int g = blockIdx.x;
    int cbase, n0, nseg;
    if (g < CB1)       { cbase = IC2; n0 = g << 9;            nseg = N3; }
    else if (g < CB0S) { cbase = IC1; n0 = (g - CB1) << 9;    nseg = N2; }
    else if (g < CB0D) { cbase = I0S; n0 = (g - CB0S) << 9;   nseg = N1; }
    else               { cbase = I0D; n0 = (g - CB0D) << 9;   nseg = N1; }
    int nodes = nseg - n0; if (nodes > 512) nodes = 512;
    int cnt = bcnt[g]; if (cnt > SLAB) cnt = SLAB;
    int R0 = g * SLAB;
    lcnt[t] = 0; lcnt[t + 256] = 0;
    // stage slab region into LDS
    for (int i = t; i < cnt; i += 256) ent[i] = cpool[R0 + i];
    __syncthreads();
    // per-node counts
    for (int i = t; i < cnt; i += 256) atomicAdd(&lcnt[ent[i] >> 18], 1);
    __syncthreads();
    // inclusive scan (512 entries, Hillis-Steele)
    lexc[t] = lcnt[t]; lexc[t + 256] = lcnt[t + 256];
    __syncthreads();
    for (int off = 1; off < 512; off <<= 1) {
        int a0 = (t >= off) ? lexc[t - off] : 0;
        int a1 = (t + 256 >= off) ? lexc[t + 256 - off] : 0;
        __syncthreads();
        lexc[t] += a0; lexc[t + 256] += a1;
        __syncthreads();
    }
    // emit per-node CSR; make exclusive; reset cursor
#pragma unroll
    for (int jj = 0; jj < 2; jj++) {
        int j = t + jj * 256;
        int c = lcnt[j];
        int ex = lexc[j] - c;
        if (j < nodes) { cntN[cbase + n0 + j] = c; offsN[cbase + n0 + j] = R0 + ex; }
        lexc[j] = ex; lcnt[j] = 0;
    }
    __syncthreads();
    // scatter payloads into node-sorted slots
    for (int i = t; i < cnt; i += 256) {
        int p = ent[i];
        int low = p >> 18;
        int r = atomicAdd(&lcnt[low], 1);
        pool[R0 + lexc[low] + r] = p & 0x3FFFF;
    }
}

// ---------------- layer 0: pure REW gather-sum -> h1 (bf16). No LDS, no sync. ----------------
__global__ __launch_bounds__(256) void k_layer0r(const int* __restrict__ cntN, const int* __restrict__ offsN,
                                                 const int* __restrict__ pool, const float* __restrict__ REW,
                                                 const float* __restrict__ b_out, const float* __restrict__ b_in,
                                                 const int* __restrict__ deg1o, __bf16* __restrict__ h1b) {
    int t = threadIdx.x;
    int nl = t >> 6;
    int lane = t & 63;
    int half = lane >> 5;   // 0 = out(src-agg), 1 = in(dst-agg)
    int k = lane & 31;
    int n = blockIdx.x * 4 + nl;        // grid exact: N1 % 4 == 0
    int ci = (half ? I0D : I0S) + n;
    int dg = cntN[ci];
    int off = offsN[ci];
    const float* R = REW + half * 16000;
    float acc = 0.0f;
    for (int cb = 0; cb < dg; cb += 32) {
        int rem = dg - cb; if (rem > 32) rem = 32;
        int ty_all = (k < rem) ? pool[off + cb + k] : 0;
        int i2 = 0;
        for (; i2 + 4 <= rem; i2 += 4) {
            int t0 = __shfl(ty_all, i2,     32);
            int t1 = __shfl(ty_all, i2 + 1, 32);
            int t2 = __shfl(ty_all, i2 + 2, 32);
            int t3 = __shfl(ty_all, i2 + 3, 32);
            float a0 = R[t0 * 32 + k];
            float a1 = R[t1 * 32 + k];
            float a2 = R[t2 * 32 + k];
            float a3 = R[t3 * 32 + k];
            acc += a0; acc += a1; acc += a2; acc += a3;
        }
        for (; i2 < rem; i2++) {
            int ty = __shfl(ty_all, i2, 32);
            acc += R[ty * 32 + k];
        }
    }
    float b = half ? b_in[k] : b_out[k];
    float r = (dg > 0) ? (acc / (float)dg + b) : 0.0f;
    h1b[(size_t)n * 64 + lane] = (__bf16)(r * rsqrtf(fmaxf((float)deg1o[n], 1.0f)));
}

// ---------------- conv1 with fused gather: bf16 h1, 2 edges per wave-step ----------------
__global__ __launch_bounds__(256) void k_conv1g(const __bf16* __restrict__ h1b,
                                                const int* __restrict__ cntN, const int* __restrict__ offsN,
                                                const int* __restrict__ pool, const int* __restrict__ deg2o,
                                                const float* __restrict__ W1, const float* __restrict__ b1,
                                                __bf16* __restrict__ h2b) {
    __shared__ float row[8][64];
    int base = blockIdx.x * 8;
    int t = threadIdx.x;
    int wave = t >> 6, lane = t & 63;
    int eo = lane >> 5;      // which of the 2 concurrent edges this lane serves
    int c = lane & 31;       // uint column (covers bf16 cols 2c, 2c+1)
#pragma unroll
    for (int rr = 0; rr < 2; rr++) {
        int m = wave * 2 + rr;
        int rg = base + m;                       // grid exact: rg < N2
        int dg = cntN[IC1 + rg];
        int off = offsN[IC1 + rg];
        float a0 = 0.f, a1 = 0.f;
        for (int cb = 0; cb < dg; cb += 64) {
            int rem = dg - cb; if (rem > 64) rem = 64;
            int s_all = (lane < rem) ? pool[off + cb + lane] : 0;
            int i = 0;
            for (; i + 8 <= rem; i += 8) {
                int sA = __shfl(s_all, i     + eo, 64);
                int sB = __shfl(s_all, i + 2 + eo, 64);
                int sC = __shfl(s_all, i + 4 + eo, 64);
                int sD = __shfl(s_all, i + 6 + eo, 64);
                union { unsigned u; __bf16 b[2]; } vA, vB, vC, vD;
                vA.u = *(const unsigned*)(h1b + (size_t)sA * 64 + c * 2);
                vB.u = *(const unsigned*)(h1b + (size_t)sB * 64 + c * 2);
                vC.u = *(const unsigned*)(h1b + (size_t)sC * 64 + c * 2);
                vD.u = *(const unsigned*)(h1b + (size_t)sD * 64 + c * 2);
                a0 += ((float)vA.b[0] + (float)vB.b[0]) + ((float)vC.b[0] + (float)vD.b[0]);
                a1 += ((float)vA.b[1] + (float)vB.b[1]) + ((float)vC.b[1] + (float)vD.b[1]);
            }
            for (; i < rem; i += 2) {
                int have = rem - i;              // 1 or 2
                int s = __shfl(s_all, i + ((eo < have) ? eo : 0), 64);
                union { unsigned u; __bf16 b[2]; } v;
                v.u = *(const unsigned*)(h1b + (size_t)s * 64 + c * 2);
                if (eo < have) { a0 += (float)v.b[0]; a1 += (float)v.b[1]; }
            }
        }
        a0 += __shfl_xor(a0, 32, 64);
        a1 += __shfl_xor(a1, 32, 64);
        if (eo == 0) {
            float sc = rsqrtf(fmaxf((float)dg, 1.0f));
            row[m][c * 2]     = a0 * sc;
            row[m][c * 2 + 1] = a1 * sc;
        }
    }
    __syncthreads();
    float acc8[8] = {0, 0, 0, 0, 0, 0, 0, 0};
    for (int k = 0; k < 64; k++) {
        float w = W1[k * 256 + t];
#pragma unroll
        for (int m = 0; m < 8; m++) acc8[m] += row[m][k] * w;
    }
    float bb = b1[t];
#pragma unroll
    for (int m = 0; m < 8; m++) {
        float v = fmaxf(acc8[m] + bb, 0.0f) * rsqrtf(fmaxf((float)deg2o[base + m], 1.0f));
        h2b[(size_t)(base + m) * 256 + t] = (__bf16)v;
    }
}

// ---------------- pack W (K x 256 f32, row-major) into MFMA B-fragment order (bf16) ----------------
__global__ void k_pack(const float* __restrict__ W, __bf16* __restrict__ Wp, int ksteps) {
    int idx = blockIdx.x * 256 + threadIdx.x;
    int j = idx & 7;
    int lane = (idx >> 3) & 63;
    int rest = idx >> 9;
    int ks = rest % ksteps;
    int tn = rest / ksteps;
    int k = ks * 32 + ((lane >> 4) * 8) + j;
    int n = tn * 16 + (lane & 15);
    Wp[idx] = (__bf16)W[k * 256 + n];
}

// ---------------- conv2 MFMA with fused gather (bf16 h2, unroll x4) ----------------
__global__ __launch_bounds__(256) void k_conv2g(const __bf16* __restrict__ h2b,
                                                const int* __restrict__ cntN, const int* __restrict__ offsN,
                                                const int* __restrict__ pool,
                                                const __bf16* __restrict__ W2p,
                                                const float* __restrict__ b2v,
                                                __bf16* __restrict__ x3b) {
    __shared__ __bf16 At[64][264];   // +8 pad -> 2-way LDS conflicts only
    int t = threadIdx.x;
    int base = blockIdx.x * 64;
    int wave = t >> 6, lane = t & 63;
#pragma unroll 1
    for (int rr = 0; rr < 16; rr++) {
        int row = wave * 16 + rr;
        int rg = base + row;
        float a0 = 0.f, a1 = 0.f, a2 = 0.f, a3 = 0.f;
        int dg = 0;
        if (rg < N3) {
            dg = cntN[IC2 + rg];
            int off = offsN[IC2 + rg];
            for (int cb = 0; cb < dg; cb += 64) {
                int rem = dg - cb; if (rem > 64) rem = 64;
                int s_all = (lane < rem) ? pool[off + cb + lane] : 0;
                int i = 0;
                for (; i + 4 <= rem; i += 4) {
                    int s0 = __shfl(s_all, i,     64);
                    int s1 = __shfl(s_all, i + 1, 64);
                    int s2 = __shfl(s_all, i + 2, 64);
                    int s3 = __shfl(s_all, i + 3, 64);
                    union { ushort4 u; __bf16 b[4]; } v0, v1, v2, v3;
                    v0.u = *(const ushort4*)(h2b + (size_t)s0 * 256 + lane * 4);
                    v1.u = *(const ushort4*)(h2b + (size_t)s1 * 256 + lane * 4);
                    v2.u = *(const ushort4*)(h2b + (size_t)s2 * 256 + lane * 4);
                    v3.u = *(const ushort4*)(h2b + (size_t)s3 * 256 + lane * 4);
                    a0 += ((float)v0.b[0] + (float)v1.b[0]) + ((float)v2.b[0] + (float)v3.b[0]);
                    a1 += ((float)v0.b[1] + (float)v1.b[1]) + ((float)v2.b[1] + (float)v3.b[1]);
                    a2 += ((float)v0.b[2] + (float)v1.b[2]) + ((float)v2.b[2] + (float)v3.b[2]);
                    a3 += ((float)v0.b[3] + (float)v1.b[3]) + ((float)v2.b[3] + (float)v3.b[3]);
                }
                for (; i < rem; i++) {
                    int s0 = __shfl(s_all, i, 64);
                    union { ushort4 u; __bf16 b[4]; } v0;
                    v0.u = *(const ushort4*)(h2b + (size_t)s0 * 256 + lane * 4);
                    a0 += (float)v0.b[0]; a1 += (float)v0.b[1];
                    a2 += (float)v0.b[2]; a3 += (float)v0.b[3];
                }
            }
        }
        float sc = rsqrtf(fmaxf((float)dg, 1.0f));
        union { __bf16 b[4]; uint2 u; } cv;
        cv.b[0] = (__bf16)(a0 * sc); cv.b[1] = (__bf16)(a1 * sc);
        cv.b[2] = (__bf16)(a2 * sc); cv.b[3] = (__bf16)(a3 * sc);
        *(uint2*)&At[row][lane * 4] = cv.u;
    }
    __syncthreads();
    int q = lane >> 4, r16 = lane & 15;
    f32x4 acc[4][4] = {};
    for (int ks = 0; ks < 8; ks++) {
        bf16x8 a[4], b[4];
        int ko = ks * 32 + q * 8;
#pragma unroll
        for (int mt = 0; mt < 4; mt++)
            a[mt] = *(const bf16x8*)&At[mt * 16 + r16][ko];
#pragma unroll
        for (int i = 0; i < 4; i++) {
            int tn = wave * 4 + i;
            b[i] = *(const bf16x8*)&W2p[((size_t)(tn * 8 + ks) * 64 + lane) * 8];
        }
#pragma unroll
        for (int mt = 0; mt < 4; mt++)
#pragma unroll
            for (int i = 0; i < 4; i++)
                acc[mt][i] = __builtin_amdgcn_mfma_f32_16x16x32_bf16(a[mt], b[i], acc[mt][i], 0, 0, 0);
    }
#pragma unroll
    for (int mt = 0; mt < 4; mt++) {
#pragma unroll
        for (int i = 0; i < 4; i++) {
            int col = (wave * 4 + i) * 16 + r16;
            float bb = b2v[col];
#pragma unroll
            for (int rr = 0; rr < 4; rr++) {
                int row = base + mt * 16 + q * 4 + rr;
                if (row < N3)
                    x3b[(size_t)row * 256 + col] = (__bf16)fmaxf(acc[mt][i][rr] + bb, 0.0f);
            }
        }
    }
}

// ---------------- final via MFMA: out = [x3b[ss], x3b[sd]] @ Wfc + bfc ----------------
__global__ __launch_bounds__(256) void k_final_mfma(const int* __restrict__ ss, const int* __restrict__ sd,
                                                    const __bf16* __restrict__ x3b,
                                                    const __bf16* __restrict__ Wp,
                                                    const float* __restrict__ bfc,
                                                    float* __restrict__ out) {
    __shared__ __bf16 At[64][520];   // +8 pad -> 2-way LDS conflicts only
    __shared__ int eidx[128];
    int t = threadIdx.x;
    int base = blockIdx.x * 64;
    if (t < 64)       { int e = base + t;      eidx[t] = ss[e < ESUB ? e : ESUB - 1]; }
    else if (t < 128) { int e = base + t - 64; eidx[t] = sd[e < ESUB ? e : ESUB - 1]; }
    __syncthreads();
#pragma unroll
    for (int it = 0; it < 16; it++) {
        int c = it * 256 + t;       // 0..4095
        int row = c >> 6;           // 0..63
        int cpos = c & 63;          // 16B chunk within 512-elem row
        int half = cpos >> 5;
        int off8 = (cpos & 31) * 8;
        int node = eidx[half * 64 + row];
        uint4 v = *(const uint4*)(x3b + (size_t)node * 256 + off8);
        *(uint4*)&At[row][half * 256 + off8] = v;
    }
    __syncthreads();
    int wave = t >> 6, lane = t & 63;
    int q = lane >> 4, r16 = lane & 15;
    f32x4 acc[4][4] = {};
    for (int ks = 0; ks < 16; ks++) {
        bf16x8 a[4], b[4];
        int ko = ks * 32 + q * 8;
#pragma unroll
        for (int mt = 0; mt < 4; mt++)
            a[mt] = *(const bf16x8*)&At[mt * 16 + r16][ko];
#pragma unroll
        for (int i = 0; i < 4; i++) {
            int tn = wave * 4 + i;
            b[i] = *(const bf16x8*)&Wp[((size_t)(tn * 16 + ks) * 64 + lane) * 8];
        }
#pragma unroll
        for (int mt = 0; mt < 4; mt++)
#pragma unroll
            for (int i = 0; i < 4; i++)
                acc[mt][i] = __builtin_amdgcn_mfma_f32_16x16x32_bf16(a[mt], b[i], acc[mt][i], 0, 0, 0);
    }
#pragma unroll
    for (int mt = 0; mt < 4; mt++) {
#pragma unroll
        for (int i = 0; i < 4; i++) {
            int col = (wave * 4 + i) * 16 + r16;
            float bb = bfc[col];
#pragma unroll
            for (int rr = 0; rr < 4; rr++) {
                int row = base + mt * 16 + q * 4 + rr;
                if (row < ESUB)
                    out[(size_t)row * 256 + col] = acc[mt][i][rr] + bb;
            }
        }
    }
}

extern "C" void kernel_launch(void* const* d_in, const int* in_sizes, int n_in,
                              void* d_out, int out_size, void* d_ws, size_t ws_size,
                              hipStream_t stream) {
    const int* e0_type = (const int*)d_in[0];
    const int* e0_src  = (const int*)d_in[1];
    const int* e0_dst  = (const int*)d_in[2];
    const int* e1_src  = (const int*)d_in[3];
    const int* e1_dst  = (const int*)d_in[4];
    const int* e2_src  = (const int*)d_in[5];
    const int* e2_dst  = (const int*)d_in[6];
    const int* sub_src = (const int*)d_in[7];
    const int* sub_dst = (const int*)d_in[8];
    const float* rel_emb = (const float*)d_in[9];
    const float* W_out   = (const float*)d_in[10];
    const float* b_out   = (const float*)d_in[11];
    const float* W_in    = (const float*)d_in[12];
    const float* b_in    = (const float*)d_in[13];
    const float* W1      = (const float*)d_in[14];
    const float* b1      = (const float*)d_in[15];
    const float* W2      = (const float*)d_in[16];
    const float* b2v     = (const float*)d_in[17];
    const float* Wfc     = (const float*)d_in[18];
    const float* bfc     = (const float*)d_in[19];
    float* out = (float*)d_out;

    // ---- workspace layout (4-byte units), ~205 MB, no aliasing ----
    // zeroed: [bcnt(1024) | deg1o(N1) | deg2o(N2)]
    int* bcnt  = (int*)d_ws;
    int* deg1o = bcnt + 1024;
    int* deg2o = deg1o + N1;
    // non-zeroed:
    int* cntN  = deg2o + N2;                       // LALL
    int* offsN = cntN + LALL;                      // LALL
    float* REW = (float*)(offsN + LALL);           // 2 x 500 x 32
    int* cpool = (int*)(REW + 32000);              // NBALL*SLAB slabs (pass A)
    int* pool  = cpool + (size_t)NBALL * SLAB;     // NBALL*SLAB slabs (node-sorted)
    __bf16* h1b = (__bf16*)(pool + (size_t)NBALL * SLAB);  // N1*64 bf16
    __bf16* h2b = h1b + (size_t)N1 * 64;                   // N2*256 bf16
    __bf16* x3b = h2b + (size_t)N2 * 256;                  // N3*256 bf16
    __bf16* Wfcp = x3b + (size_t)N3 * 256;                 // 512*256 bf16
    __bf16* W2p  = Wfcp + 131072;                          // 256*256 bf16

    const int BT = 256;

    // zero slab cursors + degree counters (~1.1 MB contiguous)
    hipMemsetAsync(d_ws, 0, (size_t)(1024 + N1 + N2) * sizeof(int), stream);

    // weight prep (independent of zeroed region)
    k_pack<<<512, BT, 0, stream>>>(Wfc, Wfcp, 16);
    k_pack<<<256, BT, 0, stream>>>(W2, W2p, 8);
    k_rew<<<125, BT, 0, stream>>>(rel_emb, W_out, W_in, REW);

    // pass A: slab-direct binning of all three edge lists (one kernel, one read each)
    k_binAall<<<NBA0 + NBA1 + NBA2, BT, 0, stream>>>(e0_type, e0_src, e0_dst,
                                                     e1_src, e1_dst, e2_src, e2_dst,
                                                     deg1o, deg2o, bcnt, cpool);

    // pass B: node-sort within slabs + emit per-node CSR (cntN/offsN)
    k_binBall<<<NBALL, BT, 0, stream>>>(bcnt, cpool, pool, cntN, offsN);

    // layer 0 (REW gather-sum) -> h1 (bf16)
    k_layer0r<<<N1 / 4, BT, 0, stream>>>(cntN, offsN, pool, REW, b_out, b_in, deg1o, h1b);

    // conv1 (fused gather, bf16 h1) -> h2 (bf16)
    k_conv1g<<<N2 / 8, BT, 0, stream>>>(h1b, cntN, offsN, pool, deg2o, W1, b1, h2b);

    // conv2 (fused gather, MFMA) -> x3b
    k_conv2g<<<(N3 + 63) / 64, BT, 0, stream>>>(h2b, cntN, offsN, pool, W2p, b2v, x3b);

    // final edge MLP (MFMA)
    k_final_mfma<<<(ESUB + 63) / 64, BT, 0, stream>>>(sub_src, sub_dst, x3b, Wfcp, bfc, out);
}